// Round 7
// baseline (762.016 us; speedup 1.0000x reference)
//
#include <hip/hip_runtime.h>

// DotProductAttention: H=1024, B=8, S=4096, L=64
// inputs: d_in[0]=hidden f32 [L,B,H], d_in[1]=enc f32 [B,S,2H], d_in[2]=W f32 [H,2H], d_in[3]=bias f32 [H]
// out: context f32 [B,L,H] (524288) then weights f32 [B,S,L] (2097152)
//
// FAST path (ws_size >= 209784832), round-3 restructure:
//   ctx = (softmax(scores))^T @ (enc@W^T + b)  ==  U@W^T + b  with U = w^T@enc
//   (softmax rows sum to 1 -> bias term exact). This deletes the 137 GFLOP
//   k1f GEMM and k4f's redB traffic + atomics entirely.
//   kv2: V=W^T.hidden fp32 exact -> fp16 hi/lo fragment planes
//   kcs: enc fp32 -> row-major f16 enc16 (stored); scores = enc(hi+lo)@V(hi+lo)^T fused
//   softmax k3a/b/c (exact fp32); k3c also emits watile (A-fragment fp16 weights)
//   kU:  U[ks-partial] = watile @ enc16   (MFMA, A direct-fragment, B via LDS transpose)
//   kC:  ctx = (sum Upart) @ W^T + bias   (MFMA hi/lo both operands, no atomics)
// FALLBACK path: round-2 kernels verbatim (known-pass, 986 us).

#define H_ 1024
#define B_ 8
#define S_ 4096
#define L_ 64
#define K2H 2048

typedef _Float16 f16x8 __attribute__((ext_vector_type(8)));
typedef _Float16 f16x4 __attribute__((ext_vector_type(4)));
typedef float f32x4 __attribute__((ext_vector_type(4)));

// Fragment layout (A/B operand of mfma 16x16x32 f16), rows=m-or-n, k:
//   tile = (row/16, k/32); lane = ((k%32)/8)*16 + row%16, elem = k%8
//   linear = (tile_row*NTK + tile_k)*512 + lane*8 + elem

// ---------------- kcast: fp32 [rows][2048] -> fragment-tiled fp16 hi (+ optional lo) ----------------
__global__ __launch_bounds__(256) void kcast_kernel(const float* __restrict__ src,
                                                    _Float16* __restrict__ hi,
                                                    _Float16* __restrict__ lo) {
    __shared__ float T[16][516];
    const int t = threadIdx.x;
    const int slab = blockIdx.x, ksec = blockIdx.y;
    const float* sp = src + (size_t)slab * 16 * K2H + ksec * 512;
#pragma unroll
    for (int r = 0; r < 8; r++) {
        int lin = r * 1024 + t * 4;
        int row = lin >> 9, col = lin & 511;
        float4 v = *(const float4*)(sp + (size_t)row * K2H + col);
        T[row][col] = v.x; T[row][col + 1] = v.y; T[row][col + 2] = v.z; T[row][col + 3] = v.w;
    }
    __syncthreads();
    const size_t obase = ((size_t)slab * 64 + ksec * 16) * 512;
#pragma unroll
    for (int r = 0; r < 4; r++) {
        int c = r * 256 + t;
        int kt = c >> 6, lam = c & 63;
        int m = lam & 15, kb = kt * 32 + (lam >> 4) * 8;
        f16x8 h, l;
#pragma unroll
        for (int e = 0; e < 8; e++) {
            float x = T[m][kb + e];
            _Float16 hh = (_Float16)x;
            h[e] = hh;
            l[e] = (_Float16)(x - (float)hh);
        }
        *(f16x8*)(hi + obase + (size_t)c * 8) = h;
        if (lo) *(f16x8*)(lo + obase + (size_t)c * 8) = l;
    }
}

// ---------------- kcs: enc cast (row-major f16 stored) + fused score GEMM ----------------
// grid 2048 (slab = 16 enc rows); block 256 = 4 waves.
// Wave w at step r holds the full A-fragment of local ktile r*4+w in registers;
// ksec loop accumulates all 64 ktiles (16 per wave), LDS-reduce, direct score write.
__global__ __launch_bounds__(256) void kcs_kernel(const float* __restrict__ enc,
                                                  _Float16* __restrict__ enc16,
                                                  const _Float16* __restrict__ vh,
                                                  const _Float16* __restrict__ vl,
                                                  float* __restrict__ scores) {
    __shared__ float T[16][516];
    __shared__ float P[4][16][66];
    const int t = threadIdx.x;
    const int slab = blockIdx.x;
    const int b = slab >> 8;
    const int w = t >> 6, lane = t & 63;
    const int ml = lane & 15, q = lane >> 4;
    f32x4 acc[4] = {};

    for (int ksec = 0; ksec < 4; ksec++) {
        const float* sp = enc + (size_t)slab * (16 * K2H) + ksec * 512;
#pragma unroll
        for (int r = 0; r < 8; r++) {
            int lin = r * 1024 + t * 4;
            int row = lin >> 9, col = lin & 511;
            float4 v = *(const float4*)(sp + (size_t)row * K2H + col);
            T[row][col] = v.x; T[row][col + 1] = v.y; T[row][col + 2] = v.z; T[row][col + 3] = v.w;
        }
        __syncthreads();
#pragma unroll
        for (int r = 0; r < 4; r++) {
            const int ktl = r * 4 + w;
            const int kb = ktl * 32 + q * 8;
            f16x8 h, l;
#pragma unroll
            for (int e = 0; e < 8; e++) {
                float x = T[ml][kb + e];
                _Float16 hh = (_Float16)x;
                h[e] = hh;
                l[e] = (_Float16)(x - (float)hh);
            }
            // row-major f16 store: enc16[row s][chan]  (contiguous 16B per lane)
            *(f16x8*)(enc16 + ((size_t)(slab * 16 + ml)) * K2H + ksec * 512 + kb) = h;
            // fused score MFMA: ktile global = ksec*16 + ktl
            const int ktg = ksec * 16 + ktl;
            const size_t vbase = (((size_t)(b * 4) * 64) + ktg) * 512 + (size_t)lane * 8;
#pragma unroll
            for (int lt = 0; lt < 4; lt++) {
                f16x8 bH = *(const f16x8*)(vh + vbase + (size_t)lt * 32768);
                f16x8 bL = *(const f16x8*)(vl + vbase + (size_t)lt * 32768);
                acc[lt] = __builtin_amdgcn_mfma_f32_16x16x32_f16(h, bH, acc[lt], 0, 0, 0);
                acc[lt] = __builtin_amdgcn_mfma_f32_16x16x32_f16(l, bH, acc[lt], 0, 0, 0);
                acc[lt] = __builtin_amdgcn_mfma_f32_16x16x32_f16(h, bL, acc[lt], 0, 0, 0);
            }
        }
        __syncthreads();   // T reads done before next ksec overwrite
    }
    // cross-wave reduce: partials -> scores
#pragma unroll
    for (int lt = 0; lt < 4; lt++)
#pragma unroll
        for (int r = 0; r < 4; r++)
            P[w][q * 4 + r][lt * 16 + ml] = acc[lt][r];
    __syncthreads();
    const int s0 = (slab & 255) * 16;
#pragma unroll
    for (int u = 0; u < 4; u++) {
        const int idx = u * 256 + t;
        const int srow = idx >> 6, l = idx & 63;
        float v = P[0][srow][l] + P[1][srow][l] + P[2][srow][l] + P[3][srow][l];
        scores[(size_t)b * (S_ * L_) + (size_t)(s0 + srow) * L_ + l] = v;
    }
}

// ---------------- kv2: V[b][l][k] = sum_h W[h][k]*hidden[l][b][h] (fp32) -> tiled fp16 hi/lo ----------------
__global__ __launch_bounds__(256) void kv2_kernel(const float* __restrict__ hidden,
                                                  const float* __restrict__ W,
                                                  _Float16* __restrict__ vh,
                                                  _Float16* __restrict__ vl) {
    __shared__ float Ah[64][17];
    __shared__ float Wt[16][64];
    const int b = blockIdx.x;
    const int k0 = blockIdx.y * 64;
    const int t = threadIdx.x;
    const int lt = t & 15, kt = t >> 4;
    float acc[4][4];
#pragma unroll
    for (int i = 0; i < 4; i++)
#pragma unroll
        for (int j = 0; j < 4; j++) acc[i][j] = 0.f;

    const int ar = t >> 2, ac4 = (t & 3) * 4;
    const int wrow = t >> 4, wc4 = (t & 15) * 4;

    for (int h0 = 0; h0 < H_; h0 += 16) {
        float4 av = *(const float4*)(hidden + (size_t)ar * (B_ * H_) + b * H_ + h0 + ac4);
        Ah[ar][ac4 + 0] = av.x; Ah[ar][ac4 + 1] = av.y; Ah[ar][ac4 + 2] = av.z; Ah[ar][ac4 + 3] = av.w;
        *(float4*)&Wt[wrow][wc4] = *(const float4*)(W + (size_t)(h0 + wrow) * K2H + k0 + wc4);
        __syncthreads();
#pragma unroll
        for (int hh = 0; hh < 16; hh++) {
            float a0 = Ah[lt * 4 + 0][hh], a1 = Ah[lt * 4 + 1][hh];
            float a2 = Ah[lt * 4 + 2][hh], a3 = Ah[lt * 4 + 3][hh];
            float4 wv = *(const float4*)&Wt[hh][kt * 4];
            acc[0][0] += a0 * wv.x; acc[0][1] += a0 * wv.y; acc[0][2] += a0 * wv.z; acc[0][3] += a0 * wv.w;
            acc[1][0] += a1 * wv.x; acc[1][1] += a1 * wv.y; acc[1][2] += a1 * wv.z; acc[1][3] += a1 * wv.w;
            acc[2][0] += a2 * wv.x; acc[2][1] += a2 * wv.y; acc[2][2] += a2 * wv.z; acc[2][3] += a2 * wv.w;
            acc[3][0] += a3 * wv.x; acc[3][1] += a3 * wv.y; acc[3][2] += a3 * wv.z; acc[3][3] += a3 * wv.w;
        }
        __syncthreads();
    }
#pragma unroll
    for (int i = 0; i < 4; i++) {
        const int l = lt * 4 + i;
        const int ltile = l >> 4, lam = l & 15;
#pragma unroll
        for (int j = 0; j < 4; j++) {
            const int k = k0 + kt * 4 + j;
            const size_t idx = (((size_t)(b * 4 + ltile) * 64) + (k >> 5)) * 512
                             + (size_t)((((k >> 3) & 3) * 16 + lam) * 8 + (k & 7));
            float v = acc[i][j];
            _Float16 hh = (_Float16)v;
            vh[idx] = hh;
            vl[idx] = (_Float16)(v - (float)hh);
        }
    }
}

// ---------------- kU: U[ks][b][l][chan] = sum_{s in ks-chunk} watile[l][s] * enc16[s][chan] ----------------
// grid (8 b, 32 nc, 4 ks), block 256 = 4 waves (2m x 2n). M=64 (all l), N=64 chans, K=1024 s.
// A = watile fragment (m=l, k=s) -> direct f16x8 global loads.
// B = enc16 row-major f16 staged [32 s][66 pad] in LDS, transposed read (pad=2 -> 2-way max, free).
__global__ __launch_bounds__(256) void kU_kernel(const _Float16* __restrict__ wa,
                                                 const _Float16* __restrict__ enc16,
                                                 float* __restrict__ Upart) {
    __shared__ _Float16 T[32][66];
    const int t = threadIdx.x;
    const int b = blockIdx.x, nc = blockIdx.y, ks = blockIdx.z;
    const int w = t >> 6, lane = t & 63;
    const int ml = lane & 15, q = lane >> 4;
    const int wm = w >> 1, wn = w & 1;
    f32x4 acc[2][2] = {};
    const int srow = t >> 3, scol = (t & 7) * 8;

    for (int it = 0; it < 32; ++it) {
        const int s0 = ks * 1024 + it * 32;
        *(f16x8*)&T[srow][scol] =
            *(const f16x8*)(enc16 + ((size_t)(b * S_ + s0 + srow)) * K2H + nc * 64 + scol);
        __syncthreads();
        // B fragments (n = chan, k = s): lane needs T[q*8+e][chan]
        f16x8 bf[2];
#pragma unroll
        for (int j = 0; j < 2; j++) {
            const int cb = (wn * 2 + j) * 16 + ml;
#pragma unroll
            for (int e = 0; e < 8; e++) bf[j][e] = T[q * 8 + e][cb];
        }
        const int stile = ks * 32 + it;
#pragma unroll
        for (int i = 0; i < 2; i++) {
            f16x8 a = *(const f16x8*)(wa + (((size_t)(b * 4 + wm * 2 + i)) * 128 + stile) * 512
                                       + (size_t)lane * 8);
#pragma unroll
            for (int j = 0; j < 2; j++)
                acc[i][j] = __builtin_amdgcn_mfma_f32_16x16x32_f16(a, bf[j], acc[i][j], 0, 0, 0);
        }
        __syncthreads();
    }
#pragma unroll
    for (int i = 0; i < 2; i++)
#pragma unroll
        for (int j = 0; j < 2; j++)
#pragma unroll
            for (int r = 0; r < 4; r++) {
                const int l = wm * 32 + i * 16 + q * 4 + r;
                const int ch = nc * 64 + (wn * 2 + j) * 16 + ml;
                Upart[(((size_t)(ks * 8 + b)) * 64 + l) * K2H + ch] = acc[i][j][r];
            }
}

// ---------------- kC: ctx[b][l][h] = sum_k Usum[b][l][k] * W[h][k] + bias[h] (MFMA hi/lo) ----------------
// grid (16 hc, 8 b), block 256 = 4 waves (2m x 2n). M=64 (l), N=64 (h chunk), K=2048.
// A = Usum f32 -> hi/lo split staged in LDS (ks-style). B = w16h/w16l fragments, direct global.
// Direct f32 stores: no atomics, full coverage of ctx.
__global__ __launch_bounds__(256) void kC_kernel(const float* __restrict__ Upart,
                                                 const _Float16* __restrict__ w16h,
                                                 const _Float16* __restrict__ w16l,
                                                 const float* __restrict__ bias,
                                                 float* __restrict__ ctx) {
    __shared__ _Float16 AsH[64][40], AsL[64][40];
    const int t = threadIdx.x;
    const int hc = blockIdx.x, b = blockIdx.y;
    const int w = t >> 6, lane = t & 63;
    const int ml = lane & 15, q = lane >> 4;
    const int wm = w >> 1, wn = w & 1;
    f32x4 acc[2][2] = {};
    const int r0 = t >> 2, c8 = (t & 3) * 8;

    for (int k0 = 0; k0 < K2H; k0 += 32) {
        float xv[8];
#pragma unroll
        for (int e = 0; e < 8; e++) xv[e] = 0.f;
        const size_t ub = ((size_t)b * 64 + r0) * K2H + k0 + c8;
#pragma unroll
        for (int p = 0; p < 4; p++) {
            const float* up = Upart + (size_t)p * (8 * 64 * K2H) + ub;
            float4 u0 = *(const float4*)up, u1 = *(const float4*)(up + 4);
            xv[0] += u0.x; xv[1] += u0.y; xv[2] += u0.z; xv[3] += u0.w;
            xv[4] += u1.x; xv[5] += u1.y; xv[6] += u1.z; xv[7] += u1.w;
        }
        f16x8 hh, ll;
#pragma unroll
        for (int e = 0; e < 8; e++) {
            _Float16 hv = (_Float16)xv[e];
            hh[e] = hv;
            ll[e] = (_Float16)(xv[e] - (float)hv);
        }
        *(f16x8*)&AsH[r0][c8] = hh;
        *(f16x8*)&AsL[r0][c8] = ll;
        __syncthreads();
        const int kt = k0 >> 5;
        f16x8 bH[2], bL[2];
#pragma unroll
        for (int j = 0; j < 2; j++) {
            const size_t wb = (((size_t)(hc * 4 + wn * 2 + j)) * 64 + kt) * 512 + (size_t)lane * 8;
            bH[j] = *(const f16x8*)(w16h + wb);
            bL[j] = *(const f16x8*)(w16l + wb);
        }
#pragma unroll
        for (int i = 0; i < 2; i++) {
            f16x8 aH = *(const f16x8*)&AsH[wm * 32 + i * 16 + ml][q * 8];
            f16x8 aL = *(const f16x8*)&AsL[wm * 32 + i * 16 + ml][q * 8];
#pragma unroll
            for (int j = 0; j < 2; j++) {
                acc[i][j] = __builtin_amdgcn_mfma_f32_16x16x32_f16(aH, bH[j], acc[i][j], 0, 0, 0);
                acc[i][j] = __builtin_amdgcn_mfma_f32_16x16x32_f16(aL, bH[j], acc[i][j], 0, 0, 0);
                acc[i][j] = __builtin_amdgcn_mfma_f32_16x16x32_f16(aH, bL[j], acc[i][j], 0, 0, 0);
            }
        }
        __syncthreads();
    }
#pragma unroll
    for (int i = 0; i < 2; i++)
#pragma unroll
        for (int j = 0; j < 2; j++) {
            const int h = hc * 64 + wn * 32 + j * 16 + ml;
            const float bv = bias[h];
#pragma unroll
            for (int r = 0; r < 4; r++) {
                const int l = wm * 32 + i * 16 + q * 4 + r;
                ctx[(((size_t)(b * 64 + l)) << 10) + h] = acc[i][j][r] + bv;
            }
        }
}

// ================= fallback (round-2) kernels =================

__global__ __launch_bounds__(256) void ksb_kernel(const float* __restrict__ hidden,
                                                  const float* __restrict__ bias,
                                                  float* __restrict__ sb) {
    const int b = blockIdx.x, t = threadIdx.x;
    const int l = t & 63, j = t >> 6;
    const float* hp = hidden + (size_t)l * (B_ * H_) + b * H_ + j * 256;
    const float* bp = bias + j * 256;
    float s = 0.f;
    for (int i = 0; i < 64; i++) {
        float4 h4 = *(const float4*)(hp + i * 4);
        float4 b4 = *(const float4*)(bp + i * 4);
        s += h4.x * b4.x + h4.y * b4.y + h4.z * b4.z + h4.w * b4.w;
    }
    __shared__ float red[256];
    red[t] = s; __syncthreads();
    if (t < 128) red[t] += red[t + 128];
    __syncthreads();
    if (t < 64) sb[b * 64 + t] = red[t] + red[t + 64];
}

__global__ __launch_bounds__(256) void kv_kernel(const float* __restrict__ hidden,
                                                 const float* __restrict__ W,
                                                 float* __restrict__ V) {
    __shared__ float Ah[64][17];
    __shared__ float Wt[16][64];
    const int b = blockIdx.x;
    const int k0 = blockIdx.y * 64;
    const int t = threadIdx.x;
    const int lt = t & 15, kt = t >> 4;
    float acc[4][4];
#pragma unroll
    for (int i = 0; i < 4; i++)
#pragma unroll
        for (int j = 0; j < 4; j++) acc[i][j] = 0.f;

    const int ar = t >> 2, ac4 = (t & 3) * 4;
    const int wrow = t >> 4, wc4 = (t & 15) * 4;

    for (int h0 = 0; h0 < H_; h0 += 16) {
        float4 av = *(const float4*)(hidden + (size_t)ar * (B_ * H_) + b * H_ + h0 + ac4);
        Ah[ar][ac4 + 0] = av.x; Ah[ar][ac4 + 1] = av.y; Ah[ar][ac4 + 2] = av.z; Ah[ar][ac4 + 3] = av.w;
        *(float4*)&Wt[wrow][wc4] = *(const float4*)(W + (size_t)(h0 + wrow) * K2H + k0 + wc4);
        __syncthreads();
#pragma unroll
        for (int hh = 0; hh < 16; hh++) {
            float a0 = Ah[lt * 4 + 0][hh], a1 = Ah[lt * 4 + 1][hh];
            float a2 = Ah[lt * 4 + 2][hh], a3 = Ah[lt * 4 + 3][hh];
            float4 wv = *(const float4*)&Wt[hh][kt * 4];
            acc[0][0] += a0 * wv.x; acc[0][1] += a0 * wv.y; acc[0][2] += a0 * wv.z; acc[0][3] += a0 * wv.w;
            acc[1][0] += a1 * wv.x; acc[1][1] += a1 * wv.y; acc[1][2] += a1 * wv.z; acc[1][3] += a1 * wv.w;
            acc[2][0] += a2 * wv.x; acc[2][1] += a2 * wv.y; acc[2][2] += a2 * wv.z; acc[2][3] += a2 * wv.w;
            acc[3][0] += a3 * wv.x; acc[3][1] += a3 * wv.y; acc[3][2] += a3 * wv.z; acc[3][3] += a3 * wv.w;
        }
        __syncthreads();
    }
#pragma unroll
    for (int i = 0; i < 4; i++) {
        float4 o; o.x = acc[i][0]; o.y = acc[i][1]; o.z = acc[i][2]; o.w = acc[i][3];
        *(float4*)(V + (size_t)b * (L_ * K2H) + (lt * 4 + i) * K2H + k0 + kt * 4) = o;
    }
}

__global__ __launch_bounds__(256) void k1_kernel(const float* __restrict__ enc,
                                                 const float* __restrict__ W,
                                                 const float* __restrict__ bias,
                                                 _Float16* __restrict__ reduced) {
    __shared__ _Float16 As[128][40];
    __shared__ _Float16 Bs[128][40];
    const int t = threadIdx.x;
    const int n0 = blockIdx.x * 128;
    const int m0 = blockIdx.y * 128;
    const int w = t >> 6, lane = t & 63;
    const int wr = w >> 1, wc = w & 1;
    const int ml = lane & 15, q = lane >> 4;

    f32x4 acc[4][4];
#pragma unroll
    for (int i = 0; i < 4; i++)
#pragma unroll
        for (int j = 0; j < 4; j++) acc[i][j] = (f32x4){0.f, 0.f, 0.f, 0.f};

    const int r0 = t >> 2;
    const int c8 = (t & 3) * 8;

    for (int k0 = 0; k0 < K2H; k0 += 32) {
#pragma unroll
        for (int j = 0; j < 2; ++j) {
            const int row = r0 + 64 * j;
            const float* pa = enc + (size_t)(m0 + row) * K2H + k0 + c8;
            float4 a0 = *(const float4*)pa, a1 = *(const float4*)(pa + 4);
            f16x8 ha;
            ha[0] = (_Float16)a0.x; ha[1] = (_Float16)a0.y; ha[2] = (_Float16)a0.z; ha[3] = (_Float16)a0.w;
            ha[4] = (_Float16)a1.x; ha[5] = (_Float16)a1.y; ha[6] = (_Float16)a1.z; ha[7] = (_Float16)a1.w;
            *(f16x8*)&As[row][c8] = ha;
            const float* pb = W + (size_t)(n0 + row) * K2H + k0 + c8;
            float4 b0 = *(const float4*)pb, b1 = *(const float4*)(pb + 4);
            f16x8 hb;
            hb[0] = (_Float16)b0.x; hb[1] = (_Float16)b0.y; hb[2] = (_Float16)b0.z; hb[3] = (_Float16)b0.w;
            hb[4] = (_Float16)b1.x; hb[5] = (_Float16)b1.y; hb[6] = (_Float16)b1.z; hb[7] = (_Float16)b1.w;
            *(f16x8*)&Bs[row][c8] = hb;
        }
        __syncthreads();
        f16x8 af[4], bf[4];
#pragma unroll
        for (int i = 0; i < 4; i++) af[i] = *(const f16x8*)&As[wr * 64 + i * 16 + ml][q * 8];
#pragma unroll
        for (int j = 0; j < 4; j++) bf[j] = *(const f16x8*)&Bs[wc * 64 + j * 16 + ml][q * 8];
#pragma unroll
        for (int i = 0; i < 4; i++)
#pragma unroll
            for (int j = 0; j < 4; j++)
                acc[i][j] = __builtin_amdgcn_mfma_f32_16x16x32_f16(af[i], bf[j], acc[i][j], 0, 0, 0);
        __syncthreads();
    }
#pragma unroll
    for (int j = 0; j < 4; j++) {
        const int h = n0 + wc * 64 + j * 16 + ml;
        const float bv = bias[h];
#pragma unroll
        for (int i = 0; i < 4; i++) {
            const int srow = m0 + wr * 64 + i * 16 + q * 4;
#pragma unroll
            for (int r = 0; r < 4; r++)
                reduced[(size_t)(srow + r) * H_ + h] = (_Float16)(acc[i][j][r] + bv);
        }
    }
}

__global__ __launch_bounds__(256) void ks_kernel(const float* __restrict__ enc,
                                                 const float* __restrict__ V,
                                                 const float* __restrict__ sb,
                                                 float* __restrict__ scores) {
    __shared__ _Float16 AsH[64][40], AsL[64][40];
    __shared__ _Float16 BsH[64][40], BsL[64][40];
    const int t = threadIdx.x;
    const int s0 = blockIdx.x * 64;
    const int b = blockIdx.y;
    const int w = t >> 6, lane = t & 63;
    const int ml = lane & 15, q = lane >> 4;

    f32x4 acc[4];
#pragma unroll
    for (int j = 0; j < 4; j++) acc[j] = (f32x4){0.f, 0.f, 0.f, 0.f};

    const int r0 = t >> 2, c8 = (t & 3) * 8;

    for (int k0 = 0; k0 < K2H; k0 += 32) {
        {
            const float* pa = enc + (size_t)(b * S_ + s0 + r0) * K2H + k0 + c8;
            float4 a0 = *(const float4*)pa, a1 = *(const float4*)(pa + 4);
            float xv[8] = {a0.x, a0.y, a0.z, a0.w, a1.x, a1.y, a1.z, a1.w};
            f16x8 hh, ll;
#pragma unroll
            for (int e = 0; e < 8; e++) {
                _Float16 hi = (_Float16)xv[e];
                hh[e] = hi;
                ll[e] = (_Float16)(xv[e] - (float)hi);
            }
            *(f16x8*)&AsH[r0][c8] = hh;
            *(f16x8*)&AsL[r0][c8] = ll;
        }
        {
            const float* pb = V + (size_t)b * (L_ * K2H) + (size_t)r0 * K2H + k0 + c8;
            float4 b0 = *(const float4*)pb, b1 = *(const float4*)(pb + 4);
            float xv[8] = {b0.x, b0.y, b0.z, b0.w, b1.x, b1.y, b1.z, b1.w};
            f16x8 hh, ll;
#pragma unroll
            for (int e = 0; e < 8; e++) {
                _Float16 hi = (_Float16)xv[e];
                hh[e] = hi;
                ll[e] = (_Float16)(xv[e] - (float)hi);
            }
            *(f16x8*)&BsH[r0][c8] = hh;
            *(f16x8*)&BsL[r0][c8] = ll;
        }
        __syncthreads();
        f16x8 aH = *(const f16x8*)&AsH[w * 16 + ml][q * 8];
        f16x8 aL = *(const f16x8*)&AsL[w * 16 + ml][q * 8];
#pragma unroll
        for (int j = 0; j < 4; j++) {
            f16x8 bH = *(const f16x8*)&BsH[j * 16 + ml][q * 8];
            f16x8 bL = *(const f16x8*)&BsL[j * 16 + ml][q * 8];
            acc[j] = __builtin_amdgcn_mfma_f32_16x16x32_f16(aH, bH, acc[j], 0, 0, 0);
            acc[j] = __builtin_amdgcn_mfma_f32_16x16x32_f16(aL, bH, acc[j], 0, 0, 0);
            acc[j] = __builtin_amdgcn_mfma_f32_16x16x32_f16(aH, bL, acc[j], 0, 0, 0);
        }
        __syncthreads();
    }
#pragma unroll
    for (int j = 0; j < 4; j++) {
        const int l = j * 16 + ml;
        const float sbv = sb[b * 64 + l];
        const int srow = s0 + w * 16 + q * 4;
#pragma unroll
        for (int r = 0; r < 4; r++)
            scores[(size_t)b * (S_ * L_) + (size_t)(srow + r) * L_ + l] = acc[j][r] + sbv;
    }
}

__global__ __launch_bounds__(256) void k4_kernel(const float* __restrict__ wbuf,
                                                 const _Float16* __restrict__ reduced,
                                                 float* __restrict__ ctx) {
    __shared__ float Ws[64][64];
    __shared__ _Float16 Rs[64][256];
    const int t = threadIdx.x;
    const int b = blockIdx.x, ht = blockIdx.y, sc = blockIdx.z;
    const int h = ht * 256 + t;
    float acc[64];
#pragma unroll
    for (int l = 0; l < 64; l++) acc[l] = 0.f;

    for (int cc = 0; cc < 4; ++cc) {
        const int sbase = sc * 256 + cc * 64;
#pragma unroll
        for (int j = 0; j < 4; j++) {
            int c = t + 256 * j;
            int row = c >> 4, c4 = (c & 15) * 4;
            *(float4*)&Ws[row][c4] =
                *(const float4*)(wbuf + (size_t)b * (S_ * L_) + (size_t)(sbase + row) * L_ + c4);
        }
#pragma unroll
        for (int j = 0; j < 8; j++) {
            int c = t + 256 * j;
            int row = c >> 5, ch = (c & 31) * 8;
            *(uint4*)&Rs[row][ch] =
                *(const uint4*)(reduced + (size_t)(b * S_ + sbase + row) * H_ + ht * 256 + ch);
        }
        __syncthreads();
        for (int ss = 0; ss < 64; ++ss) {
            float r = (float)Rs[ss][t];
            const float4* wr = (const float4*)&Ws[ss][0];
#pragma unroll
            for (int u = 0; u < 16; u++) {
                float4 wv = wr[u];
                acc[u * 4 + 0] += wv.x * r;
                acc[u * 4 + 1] += wv.y * r;
                acc[u * 4 + 2] += wv.z * r;
                acc[u * 4 + 3] += wv.w * r;
            }
        }
        __syncthreads();
    }
#pragma unroll
    for (int l = 0; l < 64; l++)
        atomicAdd(ctx + (size_t)((b * 64 + l) << 10) + h, acc[l]);
}

// ================= shared (both paths) =================

__global__ __launch_bounds__(256) void k3a_kernel(const float* __restrict__ scores,
                                                  float* __restrict__ partM,
                                                  float* __restrict__ partD) {
    const int b = blockIdx.x, chunk = blockIdx.y;
    const int t = threadIdx.x;
    const int l = t & 63, si = t >> 6;
    const float* p = scores + (size_t)b * (S_ * L_) + (size_t)(chunk * 256 + si * 64) * L_ + l;
    float m = -__builtin_inff(), d = 0.f;
    for (int i = 0; i < 64; i++) {
        float x = p[i * 64];
        if (x > m) { d = d * __expf(m - x) + 1.f; m = x; }
        else d += __expf(x - m);
    }
    __shared__ float sm[256], sd[256];
    sm[t] = m; sd[t] = d; __syncthreads();
    if (t < 128) {
        float m2 = sm[t + 128], d2 = sd[t + 128];
        if (m2 > sm[t]) { sd[t] = sd[t] * __expf(sm[t] - m2) + d2; sm[t] = m2; }
        else sd[t] += d2 * __expf(m2 - sm[t]);
    }
    __syncthreads();
    if (t < 64) {
        float m1 = sm[t], d1 = sd[t], m2 = sm[t + 64], d2 = sd[t + 64];
        if (m2 > m1) { d1 = d1 * __expf(m1 - m2) + d2; m1 = m2; }
        else d1 += d2 * __expf(m2 - m1);
        partM[(b * 16 + chunk) * 64 + t] = m1;
        partD[(b * 16 + chunk) * 64 + t] = d1;
    }
}

__global__ __launch_bounds__(512) void k3b_kernel(const float* __restrict__ partM,
                                                  const float* __restrict__ partD,
                                                  float* __restrict__ fm,
                                                  float* __restrict__ fdinv) {
    const int t = threadIdx.x;
    const int b = t >> 6, l = t & 63;
    float m = -__builtin_inff(), d = 0.f;
    for (int c = 0; c < 16; c++) {
        float pm = partM[(b * 16 + c) * 64 + l];
        float pd = partD[(b * 16 + c) * 64 + l];
        if (pm > m) { d = d * __expf(m - pm) + pd; m = pm; }
        else d += pd * __expf(pm - m);
    }
    fm[t] = m;
    fdinv[t] = 1.0f / d;
}

// k3c: weights = exp(x-m)*inv_d (in place fp32) + optional fp16 A-fragment transposed copy
__global__ __launch_bounds__(256) void k3c_kernel(float* __restrict__ wbuf,
                                                  const float* __restrict__ fm,
                                                  const float* __restrict__ fdinv,
                                                  _Float16* __restrict__ watile) {
    const int base = (blockIdx.x * 256 + threadIdx.x) * 8;
    const int b = base >> 18, l0 = base & 63;
    const int s = (base >> 6) & 4095;
    float4 m0 = *(const float4*)(fm + b * 64 + l0);
    float4 m1 = *(const float4*)(fm + b * 64 + l0 + 4);
    float4 i0 = *(const float4*)(fdinv + b * 64 + l0);
    float4 i1 = *(const float4*)(fdinv + b * 64 + l0 + 4);
    float4 x0 = *(const float4*)(wbuf + base);
    float4 x1 = *(const float4*)(wbuf + base + 4);
    float y[8];
    y[0] = __expf(x0.x - m0.x) * i0.x; y[1] = __expf(x0.y - m0.y) * i0.y;
    y[2] = __expf(x0.z - m0.z) * i0.z; y[3] = __expf(x0.w - m0.w) * i0.w;
    y[4] = __expf(x1.x - m1.x) * i1.x; y[5] = __expf(x1.y - m1.y) * i1.y;
    y[6] = __expf(x1.z - m1.z) * i1.z; y[7] = __expf(x1.w - m1.w) * i1.w;
    float4 o0 = {y[0], y[1], y[2], y[3]}, o1 = {y[4], y[5], y[6], y[7]};
    *(float4*)(wbuf + base) = o0;
    *(float4*)(wbuf + base + 4) = o1;
    if (watile) {
        const size_t tbase = (((size_t)(b * 4 + (l0 >> 4)) * 128) + (s >> 5)) * 512 + (size_t)(s & 7);
        const int lane_lo = ((s >> 3) & 3) * 16;
#pragma unroll
        for (int e = 0; e < 8; e++) {
            const int l = l0 + e;
            watile[tbase + (size_t)(lane_lo + (l & 15)) * 8] = (_Float16)y[e];
        }
    }
}

extern "C" void kernel_launch(void* const* d_in, const int* in_sizes, int n_in,
                              void* d_out, int out_size, void* d_ws, size_t ws_size,
                              hipStream_t stream) {
    const float* hidden = (const float*)d_in[0];
    const float* enc    = (const float*)d_in[1];
    const float* W      = (const float*)d_in[2];
    const float* bias   = (const float*)d_in[3];

    float* ctx  = (float*)d_out;
    float* wbuf = (float*)d_out + (B_ * L_ * H_);

    char* ws = (char*)d_ws;
    const size_t NEED_FAST = 209784832;

    if (ws_size >= NEED_FAST) {
        _Float16* enc16 = (_Float16*)ws;                     // 134217728 B  (B*S*2H f16)
        float*    Upart = (float*)(ws + 134217728);          //  16777216 B  (4 ks x 8 b x 64 x 2048 f32)
        _Float16* w16h  = (_Float16*)(ws + 150994944);       //   4194304 B
        _Float16* w16l  = (_Float16*)(ws + 155189248);       //   4194304 B
        _Float16* vh    = (_Float16*)(ws + 159383552);       //   2097152 B
        _Float16* vl    = (_Float16*)(ws + 161480704);       //   2097152 B
        _Float16* watile = vh;   // 4 MB alias over vh+vl (dead after kcs; written by k3c)
        float* partM = (float*)(ws + 163577856);
        float* partD = partM + 8 * 16 * 64;
        float* fm    = partD + 8 * 16 * 64;
        float* fdinv = fm + 512;

        kv2_kernel<<<dim3(8, 32), 256, 0, stream>>>(hidden, W, vh, vl);
        kcast_kernel<<<dim3(64, 4), 256, 0, stream>>>(W, w16h, w16l);
        kcs_kernel<<<2048, 256, 0, stream>>>(enc, enc16, vh, vl, wbuf);
        k3a_kernel<<<dim3(8, 16), 256, 0, stream>>>(wbuf, partM, partD);
        k3b_kernel<<<1, 512, 0, stream>>>(partM, partD, fm, fdinv);
        k3c_kernel<<<2097152 / (256 * 8), 256, 0, stream>>>(wbuf, fm, fdinv, watile);
        kU_kernel<<<dim3(8, 32, 4), 256, 0, stream>>>(watile, enc16, Upart);
        kC_kernel<<<dim3(16, 8), 256, 0, stream>>>(Upart, w16h, w16l, bias, ctx);
    } else {
        _Float16* reduced = (_Float16*)ws;                       // 67108864 B
        float* V     = (float*)(ws + 67108864);                  //  4194304 B
        float* partM = (float*)(ws + 71303168);
        float* partD = partM + 8 * 16 * 64;
        float* fm    = partD + 8 * 16 * 64;
        float* fdinv = fm + 512;
        float* sb    = fdinv + 512;

        hipMemsetAsync(ctx, 0, (size_t)B_ * L_ * H_ * sizeof(float), stream);
        ksb_kernel<<<8, 256, 0, stream>>>(hidden, bias, sb);
        kv_kernel<<<dim3(8, 32), 256, 0, stream>>>(hidden, W, V);
        k1_kernel<<<dim3(8, 256), 256, 0, stream>>>(enc, W, bias, reduced);
        ks_kernel<<<dim3(64, 8), 256, 0, stream>>>(enc, V, sb, wbuf);
        k3a_kernel<<<dim3(8, 16), 256, 0, stream>>>(wbuf, partM, partD);
        k3b_kernel<<<1, 512, 0, stream>>>(partM, partD, fm, fdinv);
        k3c_kernel<<<2097152 / (256 * 8), 256, 0, stream>>>(wbuf, fm, fdinv, (_Float16*)nullptr);
        k4_kernel<<<dim3(8, 4, 16), 256, 0, stream>>>(wbuf, reduced, ctx);
    }
}

// Round 8
// 711.221 us; speedup vs baseline: 1.0714x; 1.0714x over previous
//
#include <hip/hip_runtime.h>

// DotProductAttention: H=1024, B=8, S=4096, L=64
// inputs: d_in[0]=hidden f32 [L,B,H], d_in[1]=enc f32 [B,S,2H], d_in[2]=W f32 [H,2H], d_in[3]=bias f32 [H]
// out: context f32 [B,L,H] (524288) then weights f32 [B,S,L] (2097152)
//
// FAST path (ws_size >= 209784832):
//   ctx = (softmax(scores))^T @ (enc@W^T + b)  ==  U@W^T + b  with U = w^T@enc
//   kv2: V=W^T.hidden fp32 exact -> fp16 hi/lo fragment planes
//   kcs (r7 rework): enc fp32 -> f16 hi/lo LDS planes (cast at staging, enc16 hi
//        stored coalesced), reg double-buffered ksec staging, b128 fragment reads,
//        P reduce buffer aliased over T -> 33KB LDS, 4 blocks/CU.
//   softmax k3a/b (exact fp32); k3c (r7 rework): lane=l / 8-consecutive-s mapping,
//        watile store is one contiguous f16x8 (was 8x scattered 2B stores).
//   kU:  U[ks-partial] = watile @ enc16   (MFMA, A direct-fragment, B via LDS transpose)
//   kC:  ctx = (sum Upart) @ W^T + bias   (MFMA hi/lo both operands, no atomics)
// FALLBACK path: round-2 kernels verbatim (known-pass, 986 us).

#define H_ 1024
#define B_ 8
#define S_ 4096
#define L_ 64
#define K2H 2048

typedef _Float16 f16x8 __attribute__((ext_vector_type(8)));
typedef _Float16 f16x4 __attribute__((ext_vector_type(4)));
typedef float f32x4 __attribute__((ext_vector_type(4)));

// Fragment layout (A/B operand of mfma 16x16x32 f16), rows=m-or-n, k:
//   tile = (row/16, k/32); lane = ((k%32)/8)*16 + row%16, elem = k%8
//   linear = (tile_row*NTK + tile_k)*512 + lane*8 + elem

// ---------------- kcast: fp32 [rows][2048] -> fragment-tiled fp16 hi (+ optional lo) ----------------
__global__ __launch_bounds__(256) void kcast_kernel(const float* __restrict__ src,
                                                    _Float16* __restrict__ hi,
                                                    _Float16* __restrict__ lo) {
    __shared__ float T[16][516];
    const int t = threadIdx.x;
    const int slab = blockIdx.x, ksec = blockIdx.y;
    const float* sp = src + (size_t)slab * 16 * K2H + ksec * 512;
#pragma unroll
    for (int r = 0; r < 8; r++) {
        int lin = r * 1024 + t * 4;
        int row = lin >> 9, col = lin & 511;
        float4 v = *(const float4*)(sp + (size_t)row * K2H + col);
        T[row][col] = v.x; T[row][col + 1] = v.y; T[row][col + 2] = v.z; T[row][col + 3] = v.w;
    }
    __syncthreads();
    const size_t obase = ((size_t)slab * 64 + ksec * 16) * 512;
#pragma unroll
    for (int r = 0; r < 4; r++) {
        int c = r * 256 + t;
        int kt = c >> 6, lam = c & 63;
        int m = lam & 15, kb = kt * 32 + (lam >> 4) * 8;
        f16x8 h, l;
#pragma unroll
        for (int e = 0; e < 8; e++) {
            float x = T[m][kb + e];
            _Float16 hh = (_Float16)x;
            h[e] = hh;
            l[e] = (_Float16)(x - (float)hh);
        }
        *(f16x8*)(hi + obase + (size_t)c * 8) = h;
        if (lo) *(f16x8*)(lo + obase + (size_t)c * 8) = l;
    }
}

// ---------------- kcs: enc cast + fused score GEMM (round-7 rework) ----------------
// grid 2048 (slab = 16 enc rows); block 256 = 4 waves, 33.3KB LDS -> 4 blocks/CU.
// Staging: reg-double-buffered; cast to f16 hi/lo LDS planes + coalesced enc16 store.
// Compute: per r-step, 2x ds_read_b128 fragment loads + 24 vh/vl loads + 12 MFMA.
__global__ __launch_bounds__(256, 4) void kcs_kernel(const float* __restrict__ enc,
                                                     _Float16* __restrict__ enc16,
                                                     const _Float16* __restrict__ vh,
                                                     const _Float16* __restrict__ vl,
                                                     float* __restrict__ scores) {
    __shared__ _Float16 TT[2][16][520];   // hi/lo planes; stride 520 f16 = 16B-aligned rows
    const int t = threadIdx.x;
    const int slab = blockIdx.x;
    const int b = slab >> 8;
    const int w = t >> 6, lane = t & 63;
    const int ml = lane & 15, q = lane >> 4;
    f32x4 acc[4] = {};

    const float* sp0 = enc + (size_t)slab * (16 * K2H);
    float4 rbuf[8];
#pragma unroll
    for (int r = 0; r < 8; r++) {
        int lin = r * 1024 + t * 4;
        rbuf[r] = *(const float4*)(sp0 + (size_t)(lin >> 9) * K2H + (lin & 511));
    }

    for (int ksec = 0; ksec < 4; ksec++) {
        // write phase: cast regs -> hi/lo LDS planes + coalesced enc16 (hi) store
#pragma unroll
        for (int r = 0; r < 8; r++) {
            int lin = r * 1024 + t * 4;
            int row = lin >> 9, col = lin & 511;
            float4 v = rbuf[r];
            f16x4 h4, l4;
            h4[0] = (_Float16)v.x; h4[1] = (_Float16)v.y;
            h4[2] = (_Float16)v.z; h4[3] = (_Float16)v.w;
            l4[0] = (_Float16)(v.x - (float)h4[0]);
            l4[1] = (_Float16)(v.y - (float)h4[1]);
            l4[2] = (_Float16)(v.z - (float)h4[2]);
            l4[3] = (_Float16)(v.w - (float)h4[3]);
            *(f16x4*)&TT[0][row][col] = h4;
            *(f16x4*)&TT[1][row][col] = l4;
            *(f16x4*)(enc16 + ((size_t)(slab * 16 + row)) * K2H + ksec * 512 + col) = h4;
        }
        __syncthreads();
        // issue next ksec's global loads now; they fly under the compute phase
        if (ksec < 3) {
            const float* sp = sp0 + (ksec + 1) * 512;
#pragma unroll
            for (int r = 0; r < 8; r++) {
                int lin = r * 1024 + t * 4;
                rbuf[r] = *(const float4*)(sp + (size_t)(lin >> 9) * K2H + (lin & 511));
            }
        }
        // compute phase
#pragma unroll
        for (int r = 0; r < 4; r++) {
            const int ktl = r * 4 + w;
            const int kb = ktl * 32 + q * 8;
            f16x8 h = *(const f16x8*)&TT[0][ml][kb];
            f16x8 l = *(const f16x8*)&TT[1][ml][kb];
            const int ktg = ksec * 16 + ktl;
            const size_t vbase = (((size_t)(b * 4) * 64) + ktg) * 512 + (size_t)lane * 8;
#pragma unroll
            for (int lt = 0; lt < 4; lt++) {
                f16x8 bH = *(const f16x8*)(vh + vbase + (size_t)lt * 32768);
                f16x8 bL = *(const f16x8*)(vl + vbase + (size_t)lt * 32768);
                acc[lt] = __builtin_amdgcn_mfma_f32_16x16x32_f16(h, bH, acc[lt], 0, 0, 0);
                acc[lt] = __builtin_amdgcn_mfma_f32_16x16x32_f16(l, bH, acc[lt], 0, 0, 0);
                acc[lt] = __builtin_amdgcn_mfma_f32_16x16x32_f16(h, bL, acc[lt], 0, 0, 0);
            }
        }
        __syncthreads();   // T consumed (also fences the P alias below on last iter)
    }
    // cross-wave reduce: partials -> scores (P aliases TT storage; T is dead)
    float (*P)[16][66] = reinterpret_cast<float (*)[16][66]>(&TT[0][0][0]);
#pragma unroll
    for (int lt = 0; lt < 4; lt++)
#pragma unroll
        for (int r = 0; r < 4; r++)
            P[w][q * 4 + r][lt * 16 + ml] = acc[lt][r];
    __syncthreads();
    const int s0 = (slab & 255) * 16;
#pragma unroll
    for (int u = 0; u < 4; u++) {
        const int idx = u * 256 + t;
        const int srow = idx >> 6, l = idx & 63;
        float v = P[0][srow][l] + P[1][srow][l] + P[2][srow][l] + P[3][srow][l];
        scores[(size_t)b * (S_ * L_) + (size_t)(s0 + srow) * L_ + l] = v;
    }
}

// ---------------- kv2: V[b][l][k] = sum_h W[h][k]*hidden[l][b][h] (fp32) -> tiled fp16 hi/lo ----------------
__global__ __launch_bounds__(256) void kv2_kernel(const float* __restrict__ hidden,
                                                  const float* __restrict__ W,
                                                  _Float16* __restrict__ vh,
                                                  _Float16* __restrict__ vl) {
    __shared__ float Ah[64][17];
    __shared__ float Wt[16][64];
    const int b = blockIdx.x;
    const int k0 = blockIdx.y * 64;
    const int t = threadIdx.x;
    const int lt = t & 15, kt = t >> 4;
    float acc[4][4];
#pragma unroll
    for (int i = 0; i < 4; i++)
#pragma unroll
        for (int j = 0; j < 4; j++) acc[i][j] = 0.f;

    const int ar = t >> 2, ac4 = (t & 3) * 4;
    const int wrow = t >> 4, wc4 = (t & 15) * 4;

    for (int h0 = 0; h0 < H_; h0 += 16) {
        float4 av = *(const float4*)(hidden + (size_t)ar * (B_ * H_) + b * H_ + h0 + ac4);
        Ah[ar][ac4 + 0] = av.x; Ah[ar][ac4 + 1] = av.y; Ah[ar][ac4 + 2] = av.z; Ah[ar][ac4 + 3] = av.w;
        *(float4*)&Wt[wrow][wc4] = *(const float4*)(W + (size_t)(h0 + wrow) * K2H + k0 + wc4);
        __syncthreads();
#pragma unroll
        for (int hh = 0; hh < 16; hh++) {
            float a0 = Ah[lt * 4 + 0][hh], a1 = Ah[lt * 4 + 1][hh];
            float a2 = Ah[lt * 4 + 2][hh], a3 = Ah[lt * 4 + 3][hh];
            float4 wv = *(const float4*)&Wt[hh][kt * 4];
            acc[0][0] += a0 * wv.x; acc[0][1] += a0 * wv.y; acc[0][2] += a0 * wv.z; acc[0][3] += a0 * wv.w;
            acc[1][0] += a1 * wv.x; acc[1][1] += a1 * wv.y; acc[1][2] += a1 * wv.z; acc[1][3] += a1 * wv.w;
            acc[2][0] += a2 * wv.x; acc[2][1] += a2 * wv.y; acc[2][2] += a2 * wv.z; acc[2][3] += a2 * wv.w;
            acc[3][0] += a3 * wv.x; acc[3][1] += a3 * wv.y; acc[3][2] += a3 * wv.z; acc[3][3] += a3 * wv.w;
        }
        __syncthreads();
    }
#pragma unroll
    for (int i = 0; i < 4; i++) {
        const int l = lt * 4 + i;
        const int ltile = l >> 4, lam = l & 15;
#pragma unroll
        for (int j = 0; j < 4; j++) {
            const int k = k0 + kt * 4 + j;
            const size_t idx = (((size_t)(b * 4 + ltile) * 64) + (k >> 5)) * 512
                             + (size_t)((((k >> 3) & 3) * 16 + lam) * 8 + (k & 7));
            float v = acc[i][j];
            _Float16 hh = (_Float16)v;
            vh[idx] = hh;
            vl[idx] = (_Float16)(v - (float)hh);
        }
    }
}

// ---------------- kU: U[ks][b][l][chan] = sum_{s in ks-chunk} watile[l][s] * enc16[s][chan] ----------------
// grid (8 b, 32 nc, 4 ks), block 256 = 4 waves (2m x 2n). M=64 (all l), N=64 chans, K=1024 s.
__global__ __launch_bounds__(256) void kU_kernel(const _Float16* __restrict__ wa,
                                                 const _Float16* __restrict__ enc16,
                                                 float* __restrict__ Upart) {
    __shared__ _Float16 T[32][66];
    const int t = threadIdx.x;
    const int b = blockIdx.x, nc = blockIdx.y, ks = blockIdx.z;
    const int w = t >> 6, lane = t & 63;
    const int ml = lane & 15, q = lane >> 4;
    const int wm = w >> 1, wn = w & 1;
    f32x4 acc[2][2] = {};
    const int srow = t >> 3, scol = (t & 7) * 8;

    for (int it = 0; it < 32; ++it) {
        const int s0 = ks * 1024 + it * 32;
        *(f16x8*)&T[srow][scol] =
            *(const f16x8*)(enc16 + ((size_t)(b * S_ + s0 + srow)) * K2H + nc * 64 + scol);
        __syncthreads();
        f16x8 bf[2];
#pragma unroll
        for (int j = 0; j < 2; j++) {
            const int cb = (wn * 2 + j) * 16 + ml;
#pragma unroll
            for (int e = 0; e < 8; e++) bf[j][e] = T[q * 8 + e][cb];
        }
        const int stile = ks * 32 + it;
#pragma unroll
        for (int i = 0; i < 2; i++) {
            f16x8 a = *(const f16x8*)(wa + (((size_t)(b * 4 + wm * 2 + i)) * 128 + stile) * 512
                                       + (size_t)lane * 8);
#pragma unroll
            for (int j = 0; j < 2; j++)
                acc[i][j] = __builtin_amdgcn_mfma_f32_16x16x32_f16(a, bf[j], acc[i][j], 0, 0, 0);
        }
        __syncthreads();
    }
#pragma unroll
    for (int i = 0; i < 2; i++)
#pragma unroll
        for (int j = 0; j < 2; j++)
#pragma unroll
            for (int r = 0; r < 4; r++) {
                const int l = wm * 32 + i * 16 + q * 4 + r;
                const int ch = nc * 64 + (wn * 2 + j) * 16 + ml;
                Upart[(((size_t)(ks * 8 + b)) * 64 + l) * K2H + ch] = acc[i][j][r];
            }
}

// ---------------- kC: ctx[b][l][h] = sum_k Usum[b][l][k] * W[h][k] + bias[h] (MFMA hi/lo) ----------------
__global__ __launch_bounds__(256) void kC_kernel(const float* __restrict__ Upart,
                                                 const _Float16* __restrict__ w16h,
                                                 const _Float16* __restrict__ w16l,
                                                 const float* __restrict__ bias,
                                                 float* __restrict__ ctx) {
    __shared__ _Float16 AsH[64][40], AsL[64][40];
    const int t = threadIdx.x;
    const int hc = blockIdx.x, b = blockIdx.y;
    const int w = t >> 6, lane = t & 63;
    const int ml = lane & 15, q = lane >> 4;
    const int wm = w >> 1, wn = w & 1;
    f32x4 acc[2][2] = {};
    const int r0 = t >> 2, c8 = (t & 3) * 8;

    for (int k0 = 0; k0 < K2H; k0 += 32) {
        float xv[8];
#pragma unroll
        for (int e = 0; e < 8; e++) xv[e] = 0.f;
        const size_t ub = ((size_t)b * 64 + r0) * K2H + k0 + c8;
#pragma unroll
        for (int p = 0; p < 4; p++) {
            const float* up = Upart + (size_t)p * (8 * 64 * K2H) + ub;
            float4 u0 = *(const float4*)up, u1 = *(const float4*)(up + 4);
            xv[0] += u0.x; xv[1] += u0.y; xv[2] += u0.z; xv[3] += u0.w;
            xv[4] += u1.x; xv[5] += u1.y; xv[6] += u1.z; xv[7] += u1.w;
        }
        f16x8 hh, ll;
#pragma unroll
        for (int e = 0; e < 8; e++) {
            _Float16 hv = (_Float16)xv[e];
            hh[e] = hv;
            ll[e] = (_Float16)(xv[e] - (float)hv);
        }
        *(f16x8*)&AsH[r0][c8] = hh;
        *(f16x8*)&AsL[r0][c8] = ll;
        __syncthreads();
        const int kt = k0 >> 5;
        f16x8 bH[2], bL[2];
#pragma unroll
        for (int j = 0; j < 2; j++) {
            const size_t wb = (((size_t)(hc * 4 + wn * 2 + j)) * 64 + kt) * 512 + (size_t)lane * 8;
            bH[j] = *(const f16x8*)(w16h + wb);
            bL[j] = *(const f16x8*)(w16l + wb);
        }
#pragma unroll
        for (int i = 0; i < 2; i++) {
            f16x8 aH = *(const f16x8*)&AsH[wm * 32 + i * 16 + ml][q * 8];
            f16x8 aL = *(const f16x8*)&AsL[wm * 32 + i * 16 + ml][q * 8];
#pragma unroll
            for (int j = 0; j < 2; j++) {
                acc[i][j] = __builtin_amdgcn_mfma_f32_16x16x32_f16(aH, bH[j], acc[i][j], 0, 0, 0);
                acc[i][j] = __builtin_amdgcn_mfma_f32_16x16x32_f16(aL, bH[j], acc[i][j], 0, 0, 0);
                acc[i][j] = __builtin_amdgcn_mfma_f32_16x16x32_f16(aH, bL[j], acc[i][j], 0, 0, 0);
            }
        }
        __syncthreads();
    }
#pragma unroll
    for (int i = 0; i < 2; i++)
#pragma unroll
        for (int j = 0; j < 2; j++) {
            const int h = hc * 64 + wn * 32 + j * 16 + ml;
            const float bv = bias[h];
#pragma unroll
            for (int r = 0; r < 4; r++) {
                const int l = wm * 32 + i * 16 + q * 4 + r;
                ctx[(((size_t)(b * 64 + l)) << 10) + h] = acc[i][j][r] + bv;
            }
        }
}

// ================= fallback (round-2) kernels =================

__global__ __launch_bounds__(256) void ksb_kernel(const float* __restrict__ hidden,
                                                  const float* __restrict__ bias,
                                                  float* __restrict__ sb) {
    const int b = blockIdx.x, t = threadIdx.x;
    const int l = t & 63, j = t >> 6;
    const float* hp = hidden + (size_t)l * (B_ * H_) + b * H_ + j * 256;
    const float* bp = bias + j * 256;
    float s = 0.f;
    for (int i = 0; i < 64; i++) {
        float4 h4 = *(const float4*)(hp + i * 4);
        float4 b4 = *(const float4*)(bp + i * 4);
        s += h4.x * b4.x + h4.y * b4.y + h4.z * b4.z + h4.w * b4.w;
    }
    __shared__ float red[256];
    red[t] = s; __syncthreads();
    if (t < 128) red[t] += red[t + 128];
    __syncthreads();
    if (t < 64) sb[b * 64 + t] = red[t] + red[t + 64];
}

__global__ __launch_bounds__(256) void kv_kernel(const float* __restrict__ hidden,
                                                 const float* __restrict__ W,
                                                 float* __restrict__ V) {
    __shared__ float Ah[64][17];
    __shared__ float Wt[16][64];
    const int b = blockIdx.x;
    const int k0 = blockIdx.y * 64;
    const int t = threadIdx.x;
    const int lt = t & 15, kt = t >> 4;
    float acc[4][4];
#pragma unroll
    for (int i = 0; i < 4; i++)
#pragma unroll
        for (int j = 0; j < 4; j++) acc[i][j] = 0.f;

    const int ar = t >> 2, ac4 = (t & 3) * 4;
    const int wrow = t >> 4, wc4 = (t & 15) * 4;

    for (int h0 = 0; h0 < H_; h0 += 16) {
        float4 av = *(const float4*)(hidden + (size_t)ar * (B_ * H_) + b * H_ + h0 + ac4);
        Ah[ar][ac4 + 0] = av.x; Ah[ar][ac4 + 1] = av.y; Ah[ar][ac4 + 2] = av.z; Ah[ar][ac4 + 3] = av.w;
        *(float4*)&Wt[wrow][wc4] = *(const float4*)(W + (size_t)(h0 + wrow) * K2H + k0 + wc4);
        __syncthreads();
#pragma unroll
        for (int hh = 0; hh < 16; hh++) {
            float a0 = Ah[lt * 4 + 0][hh], a1 = Ah[lt * 4 + 1][hh];
            float a2 = Ah[lt * 4 + 2][hh], a3 = Ah[lt * 4 + 3][hh];
            float4 wv = *(const float4*)&Wt[hh][kt * 4];
            acc[0][0] += a0 * wv.x; acc[0][1] += a0 * wv.y; acc[0][2] += a0 * wv.z; acc[0][3] += a0 * wv.w;
            acc[1][0] += a1 * wv.x; acc[1][1] += a1 * wv.y; acc[1][2] += a1 * wv.z; acc[1][3] += a1 * wv.w;
            acc[2][0] += a2 * wv.x; acc[2][1] += a2 * wv.y; acc[2][2] += a2 * wv.z; acc[2][3] += a2 * wv.w;
            acc[3][0] += a3 * wv.x; acc[3][1] += a3 * wv.y; acc[3][2] += a3 * wv.z; acc[3][3] += a3 * wv.w;
        }
        __syncthreads();
    }
#pragma unroll
    for (int i = 0; i < 4; i++) {
        float4 o; o.x = acc[i][0]; o.y = acc[i][1]; o.z = acc[i][2]; o.w = acc[i][3];
        *(float4*)(V + (size_t)b * (L_ * K2H) + (lt * 4 + i) * K2H + k0 + kt * 4) = o;
    }
}

__global__ __launch_bounds__(256) void k1_kernel(const float* __restrict__ enc,
                                                 const float* __restrict__ W,
                                                 const float* __restrict__ bias,
                                                 _Float16* __restrict__ reduced) {
    __shared__ _Float16 As[128][40];
    __shared__ _Float16 Bs[128][40];
    const int t = threadIdx.x;
    const int n0 = blockIdx.x * 128;
    const int m0 = blockIdx.y * 128;
    const int w = t >> 6, lane = t & 63;
    const int wr = w >> 1, wc = w & 1;
    const int ml = lane & 15, q = lane >> 4;

    f32x4 acc[4][4];
#pragma unroll
    for (int i = 0; i < 4; i++)
#pragma unroll
        for (int j = 0; j < 4; j++) acc[i][j] = (f32x4){0.f, 0.f, 0.f, 0.f};

    const int r0 = t >> 2;
    const int c8 = (t & 3) * 8;

    for (int k0 = 0; k0 < K2H; k0 += 32) {
#pragma unroll
        for (int j = 0; j < 2; ++j) {
            const int row = r0 + 64 * j;
            const float* pa = enc + (size_t)(m0 + row) * K2H + k0 + c8;
            float4 a0 = *(const float4*)pa, a1 = *(const float4*)(pa + 4);
            f16x8 ha;
            ha[0] = (_Float16)a0.x; ha[1] = (_Float16)a0.y; ha[2] = (_Float16)a0.z; ha[3] = (_Float16)a0.w;
            ha[4] = (_Float16)a1.x; ha[5] = (_Float16)a1.y; ha[6] = (_Float16)a1.z; ha[7] = (_Float16)a1.w;
            *(f16x8*)&As[row][c8] = ha;
            const float* pb = W + (size_t)(n0 + row) * K2H + k0 + c8;
            float4 b0 = *(const float4*)pb, b1 = *(const float4*)(pb + 4);
            f16x8 hb;
            hb[0] = (_Float16)b0.x; hb[1] = (_Float16)b0.y; hb[2] = (_Float16)b0.z; hb[3] = (_Float16)b0.w;
            hb[4] = (_Float16)b1.x; hb[5] = (_Float16)b1.y; hb[6] = (_Float16)b1.z; hb[7] = (_Float16)b1.w;
            *(f16x8*)&Bs[row][c8] = hb;
        }
        __syncthreads();
        f16x8 af[4], bf[4];
#pragma unroll
        for (int i = 0; i < 4; i++) af[i] = *(const f16x8*)&As[wr * 64 + i * 16 + ml][q * 8];
#pragma unroll
        for (int j = 0; j < 4; j++) bf[j] = *(const f16x8*)&Bs[wc * 64 + j * 16 + ml][q * 8];
#pragma unroll
        for (int i = 0; i < 4; i++)
#pragma unroll
            for (int j = 0; j < 4; j++)
                acc[i][j] = __builtin_amdgcn_mfma_f32_16x16x32_f16(af[i], bf[j], acc[i][j], 0, 0, 0);
        __syncthreads();
    }
#pragma unroll
    for (int j = 0; j < 4; j++) {
        const int h = n0 + wc * 64 + j * 16 + ml;
        const float bv = bias[h];
#pragma unroll
        for (int i = 0; i < 4; i++) {
            const int srow = m0 + wr * 64 + i * 16 + q * 4;
#pragma unroll
            for (int r = 0; r < 4; r++)
                reduced[(size_t)(srow + r) * H_ + h] = (_Float16)(acc[i][j][r] + bv);
        }
    }
}

__global__ __launch_bounds__(256) void ks_kernel(const float* __restrict__ enc,
                                                 const float* __restrict__ V,
                                                 const float* __restrict__ sb,
                                                 float* __restrict__ scores) {
    __shared__ _Float16 AsH[64][40], AsL[64][40];
    __shared__ _Float16 BsH[64][40], BsL[64][40];
    const int t = threadIdx.x;
    const int s0 = blockIdx.x * 64;
    const int b = blockIdx.y;
    const int w = t >> 6, lane = t & 63;
    const int ml = lane & 15, q = lane >> 4;

    f32x4 acc[4];
#pragma unroll
    for (int j = 0; j < 4; j++) acc[j] = (f32x4){0.f, 0.f, 0.f, 0.f};

    const int r0 = t >> 2, c8 = (t & 3) * 8;

    for (int k0 = 0; k0 < K2H; k0 += 32) {
        {
            const float* pa = enc + (size_t)(b * S_ + s0 + r0) * K2H + k0 + c8;
            float4 a0 = *(const float4*)pa, a1 = *(const float4*)(pa + 4);
            float xv[8] = {a0.x, a0.y, a0.z, a0.w, a1.x, a1.y, a1.z, a1.w};
            f16x8 hh, ll;
#pragma unroll
            for (int e = 0; e < 8; e++) {
                _Float16 hi = (_Float16)xv[e];
                hh[e] = hi;
                ll[e] = (_Float16)(xv[e] - (float)hi);
            }
            *(f16x8*)&AsH[r0][c8] = hh;
            *(f16x8*)&AsL[r0][c8] = ll;
        }
        {
            const float* pb = V + (size_t)b * (L_ * K2H) + (size_t)r0 * K2H + k0 + c8;
            float4 b0 = *(const float4*)pb, b1 = *(const float4*)(pb + 4);
            float xv[8] = {b0.x, b0.y, b0.z, b0.w, b1.x, b1.y, b1.z, b1.w};
            f16x8 hh, ll;
#pragma unroll
            for (int e = 0; e < 8; e++) {
                _Float16 hi = (_Float16)xv[e];
                hh[e] = hi;
                ll[e] = (_Float16)(xv[e] - (float)hi);
            }
            *(f16x8*)&BsH[r0][c8] = hh;
            *(f16x8*)&BsL[r0][c8] = ll;
        }
        __syncthreads();
        f16x8 aH = *(const f16x8*)&AsH[w * 16 + ml][q * 8];
        f16x8 aL = *(const f16x8*)&AsL[w * 16 + ml][q * 8];
#pragma unroll
        for (int j = 0; j < 4; j++) {
            f16x8 bH = *(const f16x8*)&BsH[j * 16 + ml][q * 8];
            f16x8 bL = *(const f16x8*)&BsL[j * 16 + ml][q * 8];
            acc[j] = __builtin_amdgcn_mfma_f32_16x16x32_f16(aH, bH, acc[j], 0, 0, 0);
            acc[j] = __builtin_amdgcn_mfma_f32_16x16x32_f16(aL, bH, acc[j], 0, 0, 0);
            acc[j] = __builtin_amdgcn_mfma_f32_16x16x32_f16(aH, bL, acc[j], 0, 0, 0);
        }
        __syncthreads();
    }
#pragma unroll
    for (int j = 0; j < 4; j++) {
        const int l = j * 16 + ml;
        const float sbv = sb[b * 64 + l];
        const int srow = s0 + w * 16 + q * 4;
#pragma unroll
        for (int r = 0; r < 4; r++)
            scores[(size_t)b * (S_ * L_) + (size_t)(srow + r) * L_ + l] = acc[j][r] + sbv;
    }
}

__global__ __launch_bounds__(256) void k4_kernel(const float* __restrict__ wbuf,
                                                 const _Float16* __restrict__ reduced,
                                                 float* __restrict__ ctx) {
    __shared__ float Ws[64][64];
    __shared__ _Float16 Rs[64][256];
    const int t = threadIdx.x;
    const int b = blockIdx.x, ht = blockIdx.y, sc = blockIdx.z;
    const int h = ht * 256 + t;
    float acc[64];
#pragma unroll
    for (int l = 0; l < 64; l++) acc[l] = 0.f;

    for (int cc = 0; cc < 4; ++cc) {
        const int sbase = sc * 256 + cc * 64;
#pragma unroll
        for (int j = 0; j < 4; j++) {
            int c = t + 256 * j;
            int row = c >> 4, c4 = (c & 15) * 4;
            *(float4*)&Ws[row][c4] =
                *(const float4*)(wbuf + (size_t)b * (S_ * L_) + (size_t)(sbase + row) * L_ + c4);
        }
#pragma unroll
        for (int j = 0; j < 8; j++) {
            int c = t + 256 * j;
            int row = c >> 5, ch = (c & 31) * 8;
            *(uint4*)&Rs[row][ch] =
                *(const uint4*)(reduced + (size_t)(b * S_ + sbase + row) * H_ + ht * 256 + ch);
        }
        __syncthreads();
        for (int ss = 0; ss < 64; ++ss) {
            float r = (float)Rs[ss][t];
            const float4* wr = (const float4*)&Ws[ss][0];
#pragma unroll
            for (int u = 0; u < 16; u++) {
                float4 wv = wr[u];
                acc[u * 4 + 0] += wv.x * r;
                acc[u * 4 + 1] += wv.y * r;
                acc[u * 4 + 2] += wv.z * r;
                acc[u * 4 + 3] += wv.w * r;
            }
        }
        __syncthreads();
    }
#pragma unroll
    for (int l = 0; l < 64; l++)
        atomicAdd(ctx + (size_t)((b * 64 + l) << 10) + h, acc[l]);
}

// ================= shared (both paths) =================

__global__ __launch_bounds__(256) void k3a_kernel(const float* __restrict__ scores,
                                                  float* __restrict__ partM,
                                                  float* __restrict__ partD) {
    const int b = blockIdx.x, chunk = blockIdx.y;
    const int t = threadIdx.x;
    const int l = t & 63, si = t >> 6;
    const float* p = scores + (size_t)b * (S_ * L_) + (size_t)(chunk * 256 + si * 64) * L_ + l;
    float m = -__builtin_inff(), d = 0.f;
    for (int i = 0; i < 64; i++) {
        float x = p[i * 64];
        if (x > m) { d = d * __expf(m - x) + 1.f; m = x; }
        else d += __expf(x - m);
    }
    __shared__ float sm[256], sd[256];
    sm[t] = m; sd[t] = d; __syncthreads();
    if (t < 128) {
        float m2 = sm[t + 128], d2 = sd[t + 128];
        if (m2 > sm[t]) { sd[t] = sd[t] * __expf(sm[t] - m2) + d2; sm[t] = m2; }
        else sd[t] += d2 * __expf(m2 - sm[t]);
    }
    __syncthreads();
    if (t < 64) {
        float m1 = sm[t], d1 = sd[t], m2 = sm[t + 64], d2 = sd[t + 64];
        if (m2 > m1) { d1 = d1 * __expf(m1 - m2) + d2; m1 = m2; }
        else d1 += d2 * __expf(m2 - m1);
        partM[(b * 16 + chunk) * 64 + t] = m1;
        partD[(b * 16 + chunk) * 64 + t] = d1;
    }
}

__global__ __launch_bounds__(512) void k3b_kernel(const float* __restrict__ partM,
                                                  const float* __restrict__ partD,
                                                  float* __restrict__ fm,
                                                  float* __restrict__ fdinv) {
    const int t = threadIdx.x;
    const int b = t >> 6, l = t & 63;
    float m = -__builtin_inff(), d = 0.f;
    for (int c = 0; c < 16; c++) {
        float pm = partM[(b * 16 + c) * 64 + l];
        float pd = partD[(b * 16 + c) * 64 + l];
        if (pm > m) { d = d * __expf(m - pm) + pd; m = pm; }
        else d += pd * __expf(pm - m);
    }
    fm[t] = m;
    fdinv[t] = 1.0f / d;
}

// k3c (round-7 rework): lane owns one l; each thread handles 8 consecutive s.
// wbuf reads/writes stay 256B wave-coalesced; watile store is ONE contiguous f16x8.
__global__ __launch_bounds__(256) void k3c_kernel(float* __restrict__ wbuf,
                                                  const float* __restrict__ fm,
                                                  const float* __restrict__ fdinv,
                                                  _Float16* __restrict__ watile) {
    const int t = threadIdx.x;
    const int l = t & 63;
    const int g = blockIdx.x * 4 + (t >> 6);   // (b, s-octet) id, 0..4095
    const int b = g >> 9;
    const int s0 = (g & 511) * 8;
    const float m = fm[b * 64 + l];
    const float inv = fdinv[b * 64 + l];
    float* wp = wbuf + (size_t)b * (S_ * L_) + (size_t)s0 * L_ + l;
    float y[8];
#pragma unroll
    for (int i = 0; i < 8; i++) y[i] = __expf(wp[i * L_] - m) * inv;
#pragma unroll
    for (int i = 0; i < 8; i++) wp[i * L_] = y[i];
    if (watile) {
        f16x8 o;
#pragma unroll
        for (int i = 0; i < 8; i++) o[i] = (_Float16)y[i];
        const size_t woff = (((size_t)(b * 4 + (l >> 4)) * 128) + (s0 >> 5)) * 512
                          + (size_t)((((s0 >> 3) & 3) * 16 + (l & 15)) * 8);
        *(f16x8*)(watile + woff) = o;
    }
}

extern "C" void kernel_launch(void* const* d_in, const int* in_sizes, int n_in,
                              void* d_out, int out_size, void* d_ws, size_t ws_size,
                              hipStream_t stream) {
    const float* hidden = (const float*)d_in[0];
    const float* enc    = (const float*)d_in[1];
    const float* W      = (const float*)d_in[2];
    const float* bias   = (const float*)d_in[3];

    float* ctx  = (float*)d_out;
    float* wbuf = (float*)d_out + (B_ * L_ * H_);

    char* ws = (char*)d_ws;
    const size_t NEED_FAST = 209784832;

    if (ws_size >= NEED_FAST) {
        _Float16* enc16 = (_Float16*)ws;                     // 134217728 B  (B*S*2H f16)
        float*    Upart = (float*)(ws + 134217728);          //  16777216 B  (4 ks x 8 b x 64 x 2048 f32)
        _Float16* w16h  = (_Float16*)(ws + 150994944);       //   4194304 B
        _Float16* w16l  = (_Float16*)(ws + 155189248);       //   4194304 B
        _Float16* vh    = (_Float16*)(ws + 159383552);       //   2097152 B
        _Float16* vl    = (_Float16*)(ws + 161480704);       //   2097152 B
        _Float16* watile = vh;   // 4 MB alias over vh+vl (dead after kcs; written by k3c)
        float* partM = (float*)(ws + 163577856);
        float* partD = partM + 8 * 16 * 64;
        float* fm    = partD + 8 * 16 * 64;
        float* fdinv = fm + 512;

        kv2_kernel<<<dim3(8, 32), 256, 0, stream>>>(hidden, W, vh, vl);
        kcast_kernel<<<dim3(64, 4), 256, 0, stream>>>(W, w16h, w16l);
        kcs_kernel<<<2048, 256, 0, stream>>>(enc, enc16, vh, vl, wbuf);
        k3a_kernel<<<dim3(8, 16), 256, 0, stream>>>(wbuf, partM, partD);
        k3b_kernel<<<1, 512, 0, stream>>>(partM, partD, fm, fdinv);
        k3c_kernel<<<1024, 256, 0, stream>>>(wbuf, fm, fdinv, watile);
        kU_kernel<<<dim3(8, 32, 4), 256, 0, stream>>>(watile, enc16, Upart);
        kC_kernel<<<dim3(16, 8), 256, 0, stream>>>(Upart, w16h, w16l, bias, ctx);
    } else {
        _Float16* reduced = (_Float16*)ws;                       // 67108864 B
        float* V     = (float*)(ws + 67108864);                  //  4194304 B
        float* partM = (float*)(ws + 71303168);
        float* partD = partM + 8 * 16 * 64;
        float* fm    = partD + 8 * 16 * 64;
        float* fdinv = fm + 512;
        float* sb    = fdinv + 512;

        hipMemsetAsync(ctx, 0, (size_t)B_ * L_ * H_ * sizeof(float), stream);
        ksb_kernel<<<8, 256, 0, stream>>>(hidden, bias, sb);
        kv_kernel<<<dim3(8, 32), 256, 0, stream>>>(hidden, W, V);
        k1_kernel<<<dim3(8, 256), 256, 0, stream>>>(enc, W, bias, reduced);
        ks_kernel<<<dim3(64, 8), 256, 0, stream>>>(enc, V, sb, wbuf);
        k3a_kernel<<<dim3(8, 16), 256, 0, stream>>>(wbuf, partM, partD);
        k3b_kernel<<<1, 512, 0, stream>>>(partM, partD, fm, fdinv);
        k3c_kernel<<<1024, 256, 0, stream>>>(wbuf, fm, fdinv, (_Float16*)nullptr);
        k4_kernel<<<dim3(8, 4, 16), 256, 0, stream>>>(wbuf, reduced, ctx);
    }
}

// Round 11
// 638.964 us; speedup vs baseline: 1.1926x; 1.1131x over previous
//
#include <hip/hip_runtime.h>

// DotProductAttention: H=1024, B=8, S=4096, L=64
// inputs: d_in[0]=hidden f32 [L,B,H], d_in[1]=enc f32 [B,S,2H], d_in[2]=W f32 [H,2H], d_in[3]=bias f32 [H]
// out: context f32 [B,L,H] (524288) then weights f32 [B,S,L] (2097152)
//
// FAST path (ws_size >= 209784832):
//   ctx = (softmax(scores))^T @ (enc@W^T + b)  ==  U@W^T + b  with U = w^T@enc
//   kv2: V=W^T.hidden fp32 exact -> fp16 hi/lo fragment planes
//   kcs (r10 fix): enc fp32 -> f16 hi/lo LDS planes; emits encB = enc f16 hi in MFMA
//        B-fragment tiling. r10: st = (slab&255)>>1 (was slab>>1: wrote out of the
//        per-b region for b>=1, stomping encB+Upart -> ctx absmax 6.86).
//   softmax k3a/b (exact fp32); k3c: lane=l / 8-consecutive-s, contiguous f16x8 watile store.
//   kU (r8): LDS-free, barrier-free: A=watile frag, B=encB frag, both direct
//        coalesced global f16x8 loads; 8 MFMA per wave-iter.
//   kC (r8): K-split x4 (512 blocks), atomicAdd epilogue (bias from kq==0), ctx memset.
// FALLBACK path: round-2 kernels verbatim (known-pass, 986 us).

#define H_ 1024
#define B_ 8
#define S_ 4096
#define L_ 64
#define K2H 2048

typedef _Float16 f16x8 __attribute__((ext_vector_type(8)));
typedef _Float16 f16x4 __attribute__((ext_vector_type(4)));
typedef float f32x4 __attribute__((ext_vector_type(4)));

// Fragment layout (A/B operand of mfma 16x16x32 f16), rows=m-or-n, k:
//   tile = (row/16, k/32); lane = ((k%32)/8)*16 + row%16, elem = k%8
//   linear = (tile_row*NTK + tile_k)*512 + lane*8 + elem
// encB layout: [b][ct=chan/16 (128)][st=(s%4096)/32 (128)][512] with (row=chan, k=s).

// ---------------- kcast: fp32 [rows][2048] -> fragment-tiled fp16 hi (+ optional lo) ----------------
__global__ __launch_bounds__(256) void kcast_kernel(const float* __restrict__ src,
                                                    _Float16* __restrict__ hi,
                                                    _Float16* __restrict__ lo) {
    __shared__ float T[16][516];
    const int t = threadIdx.x;
    const int slab = blockIdx.x, ksec = blockIdx.y;
    const float* sp = src + (size_t)slab * 16 * K2H + ksec * 512;
#pragma unroll
    for (int r = 0; r < 8; r++) {
        int lin = r * 1024 + t * 4;
        int row = lin >> 9, col = lin & 511;
        float4 v = *(const float4*)(sp + (size_t)row * K2H + col);
        T[row][col] = v.x; T[row][col + 1] = v.y; T[row][col + 2] = v.z; T[row][col + 3] = v.w;
    }
    __syncthreads();
    const size_t obase = ((size_t)slab * 64 + ksec * 16) * 512;
#pragma unroll
    for (int r = 0; r < 4; r++) {
        int c = r * 256 + t;
        int kt = c >> 6, lam = c & 63;
        int m = lam & 15, kb = kt * 32 + (lam >> 4) * 8;
        f16x8 h, l;
#pragma unroll
        for (int e = 0; e < 8; e++) {
            float x = T[m][kb + e];
            _Float16 hh = (_Float16)x;
            h[e] = hh;
            l[e] = (_Float16)(x - (float)hh);
        }
        *(f16x8*)(hi + obase + (size_t)c * 8) = h;
        if (lo) *(f16x8*)(lo + obase + (size_t)c * 8) = l;
    }
}

// ---------------- kcs: enc cast + fused score GEMM + encB fragment emit ----------------
// grid 2048 (slab = 16 enc rows); block 256 = 4 waves, 33.3KB LDS -> 4 blocks/CU.
__global__ __launch_bounds__(256, 4) void kcs_kernel(const float* __restrict__ enc,
                                                     _Float16* __restrict__ encB,
                                                     const _Float16* __restrict__ vh,
                                                     const _Float16* __restrict__ vl,
                                                     float* __restrict__ scores) {
    __shared__ _Float16 TT[2][16][520];   // hi/lo planes; stride 520 f16 = 16B-aligned rows
    const int t = threadIdx.x;
    const int slab = blockIdx.x;
    const int b = slab >> 8;
    const int w = t >> 6, lane = t & 63;
    const int ml = lane & 15, q = lane >> 4;
    f32x4 acc[4] = {};

    const float* sp0 = enc + (size_t)slab * (16 * K2H);
    float4 rbuf[8];
#pragma unroll
    for (int r = 0; r < 8; r++) {
        int lin = r * 1024 + t * 4;
        rbuf[r] = *(const float4*)(sp0 + (size_t)(lin >> 9) * K2H + (lin & 511));
    }
    const int qb = (slab & 1) * 2;          // s%32 upper-half flag for this slab
    const int st = (slab & 255) >> 1;       // s-tile WITHIN batch b (r10 fix)

    for (int ksec = 0; ksec < 4; ksec++) {
        // write phase: cast regs -> hi/lo LDS planes
#pragma unroll
        for (int r = 0; r < 8; r++) {
            int lin = r * 1024 + t * 4;
            int row = lin >> 9, col = lin & 511;
            float4 v = rbuf[r];
            f16x4 h4, l4;
            h4[0] = (_Float16)v.x; h4[1] = (_Float16)v.y;
            h4[2] = (_Float16)v.z; h4[3] = (_Float16)v.w;
            l4[0] = (_Float16)(v.x - (float)h4[0]);
            l4[1] = (_Float16)(v.y - (float)h4[1]);
            l4[2] = (_Float16)(v.z - (float)h4[2]);
            l4[3] = (_Float16)(v.w - (float)h4[3]);
            *(f16x4*)&TT[0][row][col] = h4;
            *(f16x4*)&TT[1][row][col] = l4;
        }
        __syncthreads();
        // issue next ksec's global loads now; they fly under the compute phase
        if (ksec < 3) {
            const float* sp = sp0 + (ksec + 1) * 512;
#pragma unroll
            for (int r = 0; r < 8; r++) {
                int lin = r * 1024 + t * 4;
                rbuf[r] = *(const float4*)(sp + (size_t)(lin >> 9) * K2H + (lin & 511));
            }
        }
        // encB fragment store (reads stable TT[0]; contiguous half-tile global bursts)
#pragma unroll
        for (int p = 0; p < 4; p++) {
            const int pid = p * 256 + t;
            const int ctl = pid >> 5;              // local chan-tile 0..31
            const int w5 = pid & 31;
            const int oct = w5 >> 4, c = w5 & 15;  // s-octet in slab, chan%16
            f16x8 v;
#pragma unroll
            for (int e = 0; e < 8; e++) v[e] = TT[0][oct * 8 + e][ctl * 16 + c];
            const int ctg = ksec * 32 + ctl;
            const size_t off = (((size_t)(b * 128 + ctg)) * 128 + st) * 512
                             + (size_t)((qb + oct) * 16 + c) * 8;
            *(f16x8*)(encB + off) = v;
        }
        // compute phase
#pragma unroll
        for (int r = 0; r < 4; r++) {
            const int ktl = r * 4 + w;
            const int kb = ktl * 32 + q * 8;
            f16x8 h = *(const f16x8*)&TT[0][ml][kb];
            f16x8 l = *(const f16x8*)&TT[1][ml][kb];
            const int ktg = ksec * 16 + ktl;
            const size_t vbase = (((size_t)(b * 4) * 64) + ktg) * 512 + (size_t)lane * 8;
#pragma unroll
            for (int lt = 0; lt < 4; lt++) {
                f16x8 bH = *(const f16x8*)(vh + vbase + (size_t)lt * 32768);
                f16x8 bL = *(const f16x8*)(vl + vbase + (size_t)lt * 32768);
                acc[lt] = __builtin_amdgcn_mfma_f32_16x16x32_f16(h, bH, acc[lt], 0, 0, 0);
                acc[lt] = __builtin_amdgcn_mfma_f32_16x16x32_f16(l, bH, acc[lt], 0, 0, 0);
                acc[lt] = __builtin_amdgcn_mfma_f32_16x16x32_f16(h, bL, acc[lt], 0, 0, 0);
            }
        }
        __syncthreads();   // TT consumed before next ksec overwrite
    }
    // cross-wave reduce: partials -> scores (P aliases TT storage; TT is dead)
    float (*P)[16][66] = reinterpret_cast<float (*)[16][66]>(&TT[0][0][0]);
#pragma unroll
    for (int lt = 0; lt < 4; lt++)
#pragma unroll
        for (int r = 0; r < 4; r++)
            P[w][q * 4 + r][lt * 16 + ml] = acc[lt][r];
    __syncthreads();
    const int s0 = (slab & 255) * 16;
#pragma unroll
    for (int u = 0; u < 4; u++) {
        const int idx = u * 256 + t;
        const int srow = idx >> 6, l = idx & 63;
        float v = P[0][srow][l] + P[1][srow][l] + P[2][srow][l] + P[3][srow][l];
        scores[(size_t)b * (S_ * L_) + (size_t)(s0 + srow) * L_ + l] = v;
    }
}

// ---------------- kv2: V[b][l][k] = sum_h W[h][k]*hidden[l][b][h] (fp32) -> tiled fp16 hi/lo ----------------
__global__ __launch_bounds__(256) void kv2_kernel(const float* __restrict__ hidden,
                                                  const float* __restrict__ W,
                                                  _Float16* __restrict__ vh,
                                                  _Float16* __restrict__ vl) {
    __shared__ float Ah[64][17];
    __shared__ float Wt[16][64];
    const int b = blockIdx.x;
    const int k0 = blockIdx.y * 64;
    const int t = threadIdx.x;
    const int lt = t & 15, kt = t >> 4;
    float acc[4][4];
#pragma unroll
    for (int i = 0; i < 4; i++)
#pragma unroll
        for (int j = 0; j < 4; j++) acc[i][j] = 0.f;

    const int ar = t >> 2, ac4 = (t & 3) * 4;
    const int wrow = t >> 4, wc4 = (t & 15) * 4;

    for (int h0 = 0; h0 < H_; h0 += 16) {
        float4 av = *(const float4*)(hidden + (size_t)ar * (B_ * H_) + b * H_ + h0 + ac4);
        Ah[ar][ac4 + 0] = av.x; Ah[ar][ac4 + 1] = av.y; Ah[ar][ac4 + 2] = av.z; Ah[ar][ac4 + 3] = av.w;
        *(float4*)&Wt[wrow][wc4] = *(const float4*)(W + (size_t)(h0 + wrow) * K2H + k0 + wc4);
        __syncthreads();
#pragma unroll
        for (int hh = 0; hh < 16; hh++) {
            float a0 = Ah[lt * 4 + 0][hh], a1 = Ah[lt * 4 + 1][hh];
            float a2 = Ah[lt * 4 + 2][hh], a3 = Ah[lt * 4 + 3][hh];
            float4 wv = *(const float4*)&Wt[hh][kt * 4];
            acc[0][0] += a0 * wv.x; acc[0][1] += a0 * wv.y; acc[0][2] += a0 * wv.z; acc[0][3] += a0 * wv.w;
            acc[1][0] += a1 * wv.x; acc[1][1] += a1 * wv.y; acc[1][2] += a1 * wv.z; acc[1][3] += a1 * wv.w;
            acc[2][0] += a2 * wv.x; acc[2][1] += a2 * wv.y; acc[2][2] += a2 * wv.z; acc[2][3] += a2 * wv.w;
            acc[3][0] += a3 * wv.x; acc[3][1] += a3 * wv.y; acc[3][2] += a3 * wv.z; acc[3][3] += a3 * wv.w;
        }
        __syncthreads();
    }
#pragma unroll
    for (int i = 0; i < 4; i++) {
        const int l = lt * 4 + i;
        const int ltile = l >> 4, lam = l & 15;
#pragma unroll
        for (int j = 0; j < 4; j++) {
            const int k = k0 + kt * 4 + j;
            const size_t idx = (((size_t)(b * 4 + ltile) * 64) + (k >> 5)) * 512
                             + (size_t)((((k >> 3) & 3) * 16 + lam) * 8 + (k & 7));
            float v = acc[i][j];
            _Float16 hh = (_Float16)v;
            vh[idx] = hh;
            vl[idx] = (_Float16)(v - (float)hh);
        }
    }
}

// ---------------- kU: U[ks][b][l][chan] = sum_{s} watile[l][s] * encB[chan][s] ----------------
// grid (8 b, 32 nc, 4 ks), block 256 = 4 waves (2m x 2n). LDS-free, barrier-free:
// A and B fragments are direct coalesced global f16x8 loads (1KB/instr/wave).
__global__ __launch_bounds__(256) void kU_kernel(const _Float16* __restrict__ wa,
                                                 const _Float16* __restrict__ encB,
                                                 float* __restrict__ Upart) {
    const int t = threadIdx.x;
    const int b = blockIdx.x, nc = blockIdx.y, ks = blockIdx.z;
    const int w = t >> 6, lane = t & 63;
    const int ml = lane & 15, q = lane >> 4;
    const int wm = w >> 1, wn = w & 1;
    f32x4 acc[2][2] = {};

    for (int it = 0; it < 32; ++it) {
        const int stile = ks * 32 + it;
        f16x8 bf[2];
#pragma unroll
        for (int j = 0; j < 2; j++) {
            const int ct = nc * 4 + wn * 2 + j;
            bf[j] = *(const f16x8*)(encB + (((size_t)(b * 128 + ct)) * 128 + stile) * 512
                                     + (size_t)lane * 8);
        }
#pragma unroll
        for (int i = 0; i < 2; i++) {
            f16x8 a = *(const f16x8*)(wa + (((size_t)(b * 4 + wm * 2 + i)) * 128 + stile) * 512
                                       + (size_t)lane * 8);
#pragma unroll
            for (int j = 0; j < 2; j++)
                acc[i][j] = __builtin_amdgcn_mfma_f32_16x16x32_f16(a, bf[j], acc[i][j], 0, 0, 0);
        }
    }
#pragma unroll
    for (int i = 0; i < 2; i++)
#pragma unroll
        for (int j = 0; j < 2; j++)
#pragma unroll
            for (int r = 0; r < 4; r++) {
                const int l = wm * 32 + i * 16 + q * 4 + r;
                const int ch = nc * 64 + (wn * 2 + j) * 16 + ml;
                Upart[(((size_t)(ks * 8 + b)) * 64 + l) * K2H + ch] = acc[i][j][r];
            }
}

// ---------------- kC: ctx[b][l][h] += sum_{k in kq-quarter} Usum[b][l][k]*W[h][k] (+bias once) ----------------
// grid (16 hc, 8 b, 4 kq), block 256 = 4 waves. 512 blocks; atomic f32 accumulation.
__global__ __launch_bounds__(256) void kC_kernel(const float* __restrict__ Upart,
                                                 const _Float16* __restrict__ w16h,
                                                 const _Float16* __restrict__ w16l,
                                                 const float* __restrict__ bias,
                                                 float* __restrict__ ctx) {
    __shared__ _Float16 AsH[64][40], AsL[64][40];
    const int t = threadIdx.x;
    const int hc = blockIdx.x, b = blockIdx.y, kq = blockIdx.z;
    const int w = t >> 6, lane = t & 63;
    const int ml = lane & 15, q = lane >> 4;
    const int wm = w >> 1, wn = w & 1;
    f32x4 acc[2][2] = {};
    const int r0 = t >> 2, c8 = (t & 3) * 8;

    for (int k0 = kq * 512; k0 < kq * 512 + 512; k0 += 32) {
        float xv[8];
#pragma unroll
        for (int e = 0; e < 8; e++) xv[e] = 0.f;
        const size_t ub = ((size_t)b * 64 + r0) * K2H + k0 + c8;
#pragma unroll
        for (int p = 0; p < 4; p++) {
            const float* up = Upart + (size_t)p * (8 * 64 * K2H) + ub;
            float4 u0 = *(const float4*)up, u1 = *(const float4*)(up + 4);
            xv[0] += u0.x; xv[1] += u0.y; xv[2] += u0.z; xv[3] += u0.w;
            xv[4] += u1.x; xv[5] += u1.y; xv[6] += u1.z; xv[7] += u1.w;
        }
        f16x8 hh, ll;
#pragma unroll
        for (int e = 0; e < 8; e++) {
            _Float16 hv = (_Float16)xv[e];
            hh[e] = hv;
            ll[e] = (_Float16)(xv[e] - (float)hv);
        }
        *(f16x8*)&AsH[r0][c8] = hh;
        *(f16x8*)&AsL[r0][c8] = ll;
        __syncthreads();
        const int kt = k0 >> 5;
        f16x8 bH[2], bL[2];
#pragma unroll
        for (int j = 0; j < 2; j++) {
            const size_t wb = (((size_t)(hc * 4 + wn * 2 + j)) * 64 + kt) * 512 + (size_t)lane * 8;
            bH[j] = *(const f16x8*)(w16h + wb);
            bL[j] = *(const f16x8*)(w16l + wb);
        }
#pragma unroll
        for (int i = 0; i < 2; i++) {
            f16x8 aH = *(const f16x8*)&AsH[wm * 32 + i * 16 + ml][q * 8];
            f16x8 aL = *(const f16x8*)&AsL[wm * 32 + i * 16 + ml][q * 8];
#pragma unroll
            for (int j = 0; j < 2; j++) {
                acc[i][j] = __builtin_amdgcn_mfma_f32_16x16x32_f16(aH, bH[j], acc[i][j], 0, 0, 0);
                acc[i][j] = __builtin_amdgcn_mfma_f32_16x16x32_f16(aL, bH[j], acc[i][j], 0, 0, 0);
                acc[i][j] = __builtin_amdgcn_mfma_f32_16x16x32_f16(aH, bL[j], acc[i][j], 0, 0, 0);
            }
        }
        __syncthreads();
    }
#pragma unroll
    for (int i = 0; i < 2; i++)
#pragma unroll
        for (int j = 0; j < 2; j++) {
            const int h = hc * 64 + wn * 32 + j * 16 + ml;
            const float bv = (kq == 0) ? bias[h] : 0.f;
#pragma unroll
            for (int r = 0; r < 4; r++) {
                const int l = wm * 32 + i * 16 + q * 4 + r;
                atomicAdd(ctx + (((size_t)(b * 64 + l)) << 10) + h, acc[i][j][r] + bv);
            }
        }
}

// ================= fallback (round-2) kernels =================

__global__ __launch_bounds__(256) void ksb_kernel(const float* __restrict__ hidden,
                                                  const float* __restrict__ bias,
                                                  float* __restrict__ sb) {
    const int b = blockIdx.x, t = threadIdx.x;
    const int l = t & 63, j = t >> 6;
    const float* hp = hidden + (size_t)l * (B_ * H_) + b * H_ + j * 256;
    const float* bp = bias + j * 256;
    float s = 0.f;
    for (int i = 0; i < 64; i++) {
        float4 h4 = *(const float4*)(hp + i * 4);
        float4 b4 = *(const float4*)(bp + i * 4);
        s += h4.x * b4.x + h4.y * b4.y + h4.z * b4.z + h4.w * b4.w;
    }
    __shared__ float red[256];
    red[t] = s; __syncthreads();
    if (t < 128) red[t] += red[t + 128];
    __syncthreads();
    if (t < 64) sb[b * 64 + t] = red[t] + red[t + 64];
}

__global__ __launch_bounds__(256) void kv_kernel(const float* __restrict__ hidden,
                                                 const float* __restrict__ W,
                                                 float* __restrict__ V) {
    __shared__ float Ah[64][17];
    __shared__ float Wt[16][64];
    const int b = blockIdx.x;
    const int k0 = blockIdx.y * 64;
    const int t = threadIdx.x;
    const int lt = t & 15, kt = t >> 4;
    float acc[4][4];
#pragma unroll
    for (int i = 0; i < 4; i++)
#pragma unroll
        for (int j = 0; j < 4; j++) acc[i][j] = 0.f;

    const int ar = t >> 2, ac4 = (t & 3) * 4;
    const int wrow = t >> 4, wc4 = (t & 15) * 4;

    for (int h0 = 0; h0 < H_; h0 += 16) {
        float4 av = *(const float4*)(hidden + (size_t)ar * (B_ * H_) + b * H_ + h0 + ac4);
        Ah[ar][ac4 + 0] = av.x; Ah[ar][ac4 + 1] = av.y; Ah[ar][ac4 + 2] = av.z; Ah[ar][ac4 + 3] = av.w;
        *(float4*)&Wt[wrow][wc4] = *(const float4*)(W + (size_t)(h0 + wrow) * K2H + k0 + wc4);
        __syncthreads();
#pragma unroll
        for (int hh = 0; hh < 16; hh++) {
            float a0 = Ah[lt * 4 + 0][hh], a1 = Ah[lt * 4 + 1][hh];
            float a2 = Ah[lt * 4 + 2][hh], a3 = Ah[lt * 4 + 3][hh];
            float4 wv = *(const float4*)&Wt[hh][kt * 4];
            acc[0][0] += a0 * wv.x; acc[0][1] += a0 * wv.y; acc[0][2] += a0 * wv.z; acc[0][3] += a0 * wv.w;
            acc[1][0] += a1 * wv.x; acc[1][1] += a1 * wv.y; acc[1][2] += a1 * wv.z; acc[1][3] += a1 * wv.w;
            acc[2][0] += a2 * wv.x; acc[2][1] += a2 * wv.y; acc[2][2] += a2 * wv.z; acc[2][3] += a2 * wv.w;
            acc[3][0] += a3 * wv.x; acc[3][1] += a3 * wv.y; acc[3][2] += a3 * wv.z; acc[3][3] += a3 * wv.w;
        }
        __syncthreads();
    }
#pragma unroll
    for (int i = 0; i < 4; i++) {
        float4 o; o.x = acc[i][0]; o.y = acc[i][1]; o.z = acc[i][2]; o.w = acc[i][3];
        *(float4*)(V + (size_t)b * (L_ * K2H) + (lt * 4 + i) * K2H + k0 + kt * 4) = o;
    }
}

__global__ __launch_bounds__(256) void k1_kernel(const float* __restrict__ enc,
                                                 const float* __restrict__ W,
                                                 const float* __restrict__ bias,
                                                 _Float16* __restrict__ reduced) {
    __shared__ _Float16 As[128][40];
    __shared__ _Float16 Bs[128][40];
    const int t = threadIdx.x;
    const int n0 = blockIdx.x * 128;
    const int m0 = blockIdx.y * 128;
    const int w = t >> 6, lane = t & 63;
    const int wr = w >> 1, wc = w & 1;
    const int ml = lane & 15, q = lane >> 4;

    f32x4 acc[4][4];
#pragma unroll
    for (int i = 0; i < 4; i++)
#pragma unroll
        for (int j = 0; j < 4; j++) acc[i][j] = (f32x4){0.f, 0.f, 0.f, 0.f};

    const int r0 = t >> 2;
    const int c8 = (t & 3) * 8;

    for (int k0 = 0; k0 < K2H; k0 += 32) {
#pragma unroll
        for (int j = 0; j < 2; ++j) {
            const int row = r0 + 64 * j;
            const float* pa = enc + (size_t)(m0 + row) * K2H + k0 + c8;
            float4 a0 = *(const float4*)pa, a1 = *(const float4*)(pa + 4);
            f16x8 ha;
            ha[0] = (_Float16)a0.x; ha[1] = (_Float16)a0.y; ha[2] = (_Float16)a0.z; ha[3] = (_Float16)a0.w;
            ha[4] = (_Float16)a1.x; ha[5] = (_Float16)a1.y; ha[6] = (_Float16)a1.z; ha[7] = (_Float16)a1.w;
            *(f16x8*)&As[row][c8] = ha;
            const float* pb = W + (size_t)(n0 + row) * K2H + k0 + c8;
            float4 b0 = *(const float4*)pb, b1 = *(const float4*)(pb + 4);
            f16x8 hb;
            hb[0] = (_Float16)b0.x; hb[1] = (_Float16)b0.y; hb[2] = (_Float16)b0.z; hb[3] = (_Float16)b0.w;
            hb[4] = (_Float16)b1.x; hb[5] = (_Float16)b1.y; hb[6] = (_Float16)b1.z; hb[7] = (_Float16)b1.w;
            *(f16x8*)&Bs[row][c8] = hb;
        }
        __syncthreads();
        f16x8 af[4], bf[4];
#pragma unroll
        for (int i = 0; i < 4; i++) af[i] = *(const f16x8*)&As[wr * 64 + i * 16 + ml][q * 8];
#pragma unroll
        for (int j = 0; j < 4; j++) bf[j] = *(const f16x8*)&Bs[wc * 64 + j * 16 + ml][q * 8];
#pragma unroll
        for (int i = 0; i < 4; i++)
#pragma unroll
            for (int j = 0; j < 4; j++)
                acc[i][j] = __builtin_amdgcn_mfma_f32_16x16x32_f16(af[i], bf[j], acc[i][j], 0, 0, 0);
        __syncthreads();
    }
#pragma unroll
    for (int j = 0; j < 4; j++) {
        const int h = n0 + wc * 64 + j * 16 + ml;
        const float bv = bias[h];
#pragma unroll
        for (int i = 0; i < 4; i++) {
            const int srow = m0 + wr * 64 + i * 16 + q * 4;
#pragma unroll
            for (int r = 0; r < 4; r++)
                reduced[(size_t)(srow + r) * H_ + h] = (_Float16)(acc[i][j][r] + bv);
        }
    }
}

__global__ __launch_bounds__(256) void ks_kernel(const float* __restrict__ enc,
                                                 const float* __restrict__ V,
                                                 const float* __restrict__ sb,
                                                 float* __restrict__ scores) {
    __shared__ _Float16 AsH[64][40], AsL[64][40];
    __shared__ _Float16 BsH[64][40], BsL[64][40];
    const int t = threadIdx.x;
    const int s0 = blockIdx.x * 64;
    const int b = blockIdx.y;
    const int w = t >> 6, lane = t & 63;
    const int ml = lane & 15, q = lane >> 4;

    f32x4 acc[4];
#pragma unroll
    for (int j = 0; j < 4; j++) acc[j] = (f32x4){0.f, 0.f, 0.f, 0.f};

    const int r0 = t >> 2, c8 = (t & 3) * 8;

    for (int k0 = 0; k0 < K2H; k0 += 32) {
        {
            const float* pa = enc + (size_t)(b * S_ + s0 + r0) * K2H + k0 + c8;
            float4 a0 = *(const float4*)pa, a1 = *(const float4*)(pa + 4);
            float xv[8] = {a0.x, a0.y, a0.z, a0.w, a1.x, a1.y, a1.z, a1.w};
            f16x8 hh, ll;
#pragma unroll
            for (int e = 0; e < 8; e++) {
                _Float16 hi = (_Float16)xv[e];
                hh[e] = hi;
                ll[e] = (_Float16)(xv[e] - (float)hi);
            }
            *(f16x8*)&AsH[r0][c8] = hh;
            *(f16x8*)&AsL[r0][c8] = ll;
        }
        {
            const float* pb = V + (size_t)b * (L_ * K2H) + (size_t)r0 * K2H + k0 + c8;
            float4 b0 = *(const float4*)pb, b1 = *(const float4*)(pb + 4);
            float xv[8] = {b0.x, b0.y, b0.z, b0.w, b1.x, b1.y, b1.z, b1.w};
            f16x8 hh, ll;
#pragma unroll
            for (int e = 0; e < 8; e++) {
                _Float16 hi = (_Float16)xv[e];
                hh[e] = hi;
                ll[e] = (_Float16)(xv[e] - (float)hi);
            }
            *(f16x8*)&BsH[r0][c8] = hh;
            *(f16x8*)&BsL[r0][c8] = ll;
        }
        __syncthreads();
        f16x8 aH = *(const f16x8*)&AsH[w * 16 + ml][q * 8];
        f16x8 aL = *(const f16x8*)&AsL[w * 16 + ml][q * 8];
#pragma unroll
        for (int j = 0; j < 4; j++) {
            f16x8 bH = *(const f16x8*)&BsH[j * 16 + ml][q * 8];
            f16x8 bL = *(const f16x8*)&BsL[j * 16 + ml][q * 8];
            acc[j] = __builtin_amdgcn_mfma_f32_16x16x32_f16(aH, bH, acc[j], 0, 0, 0);
            acc[j] = __builtin_amdgcn_mfma_f32_16x16x32_f16(aL, bH, acc[j], 0, 0, 0);
            acc[j] = __builtin_amdgcn_mfma_f32_16x16x32_f16(aH, bL, acc[j], 0, 0, 0);
        }
        __syncthreads();
    }
#pragma unroll
    for (int j = 0; j < 4; j++) {
        const int l = j * 16 + ml;
        const float sbv = sb[b * 64 + l];
        const int srow = s0 + w * 16 + q * 4;
#pragma unroll
        for (int r = 0; r < 4; r++)
            scores[(size_t)b * (S_ * L_) + (size_t)(srow + r) * L_ + l] = acc[j][r] + sbv;
    }
}

__global__ __launch_bounds__(256) void k4_kernel(const float* __restrict__ wbuf,
                                                 const _Float16* __restrict__ reduced,
                                                 float* __restrict__ ctx) {
    __shared__ float Ws[64][64];
    __shared__ _Float16 Rs[64][256];
    const int t = threadIdx.x;
    const int b = blockIdx.x, ht = blockIdx.y, sc = blockIdx.z;
    const int h = ht * 256 + t;
    float acc[64];
#pragma unroll
    for (int l = 0; l < 64; l++) acc[l] = 0.f;

    for (int cc = 0; cc < 4; ++cc) {
        const int sbase = sc * 256 + cc * 64;
#pragma unroll
        for (int j = 0; j < 4; j++) {
            int c = t + 256 * j;
            int row = c >> 4, c4 = (c & 15) * 4;
            *(float4*)&Ws[row][c4] =
                *(const float4*)(wbuf + (size_t)b * (S_ * L_) + (size_t)(sbase + row) * L_ + c4);
        }
#pragma unroll
        for (int j = 0; j < 8; j++) {
            int c = t + 256 * j;
            int row = c >> 5, ch = (c & 31) * 8;
            *(uint4*)&Rs[row][ch] =
                *(const uint4*)(reduced + (size_t)(b * S_ + sbase + row) * H_ + ht * 256 + ch);
        }
        __syncthreads();
        for (int ss = 0; ss < 64; ++ss) {
            float r = (float)Rs[ss][t];
            const float4* wr = (const float4*)&Ws[ss][0];
#pragma unroll
            for (int u = 0; u < 16; u++) {
                float4 wv = wr[u];
                acc[u * 4 + 0] += wv.x * r;
                acc[u * 4 + 1] += wv.y * r;
                acc[u * 4 + 2] += wv.z * r;
                acc[u * 4 + 3] += wv.w * r;
            }
        }
        __syncthreads();
    }
#pragma unroll
    for (int l = 0; l < 64; l++)
        atomicAdd(ctx + (size_t)((b * 64 + l) << 10) + h, acc[l]);
}

// ================= shared (both paths) =================

__global__ __launch_bounds__(256) void k3a_kernel(const float* __restrict__ scores,
                                                  float* __restrict__ partM,
                                                  float* __restrict__ partD) {
    const int b = blockIdx.x, chunk = blockIdx.y;
    const int t = threadIdx.x;
    const int l = t & 63, si = t >> 6;
    const float* p = scores + (size_t)b * (S_ * L_) + (size_t)(chunk * 256 + si * 64) * L_ + l;
    float m = -__builtin_inff(), d = 0.f;
    for (int i = 0; i < 64; i++) {
        float x = p[i * 64];
        if (x > m) { d = d * __expf(m - x) + 1.f; m = x; }
        else d += __expf(x - m);
    }
    __shared__ float sm[256], sd[256];
    sm[t] = m; sd[t] = d; __syncthreads();
    if (t < 128) {
        float m2 = sm[t + 128], d2 = sd[t + 128];
        if (m2 > sm[t]) { sd[t] = sd[t] * __expf(sm[t] - m2) + d2; sm[t] = m2; }
        else sd[t] += d2 * __expf(m2 - sm[t]);
    }
    __syncthreads();
    if (t < 64) {
        float m1 = sm[t], d1 = sd[t], m2 = sm[t + 64], d2 = sd[t + 64];
        if (m2 > m1) { d1 = d1 * __expf(m1 - m2) + d2; m1 = m2; }
        else d1 += d2 * __expf(m2 - m1);
        partM[(b * 16 + chunk) * 64 + t] = m1;
        partD[(b * 16 + chunk) * 64 + t] = d1;
    }
}

__global__ __launch_bounds__(512) void k3b_kernel(const float* __restrict__ partM,
                                                  const float* __restrict__ partD,
                                                  float* __restrict__ fm,
                                                  float* __restrict__ fdinv) {
    const int t = threadIdx.x;
    const int b = t >> 6, l = t & 63;
    float m = -__builtin_inff(), d = 0.f;
    for (int c = 0; c < 16; c++) {
        float pm = partM[(b * 16 + c) * 64 + l];
        float pd = partD[(b * 16 + c) * 64 + l];
        if (pm > m) { d = d * __expf(m - pm) + pd; m = pm; }
        else d += pd * __expf(pm - m);
    }
    fm[t] = m;
    fdinv[t] = 1.0f / d;
}

// k3c: lane owns one l; each thread handles 8 consecutive s.
// wbuf reads/writes stay 256B wave-coalesced; watile store is ONE contiguous f16x8.
__global__ __launch_bounds__(256) void k3c_kernel(float* __restrict__ wbuf,
                                                  const float* __restrict__ fm,
                                                  const float* __restrict__ fdinv,
                                                  _Float16* __restrict__ watile) {
    const int t = threadIdx.x;
    const int l = t & 63;
    const int g = blockIdx.x * 4 + (t >> 6);   // (b, s-octet) id, 0..4095
    const int b = g >> 9;
    const int s0 = (g & 511) * 8;
    const float m = fm[b * 64 + l];
    const float inv = fdinv[b * 64 + l];
    float* wp = wbuf + (size_t)b * (S_ * L_) + (size_t)s0 * L_ + l;
    float y[8];
#pragma unroll
    for (int i = 0; i < 8; i++) y[i] = __expf(wp[i * L_] - m) * inv;
#pragma unroll
    for (int i = 0; i < 8; i++) wp[i * L_] = y[i];
    if (watile) {
        f16x8 o;
#pragma unroll
        for (int i = 0; i < 8; i++) o[i] = (_Float16)y[i];
        const size_t woff = (((size_t)(b * 4 + (l >> 4)) * 128) + (s0 >> 5)) * 512
                          + (size_t)((((s0 >> 3) & 3) * 16 + (l & 15)) * 8);
        *(f16x8*)(watile + woff) = o;
    }
}

extern "C" void kernel_launch(void* const* d_in, const int* in_sizes, int n_in,
                              void* d_out, int out_size, void* d_ws, size_t ws_size,
                              hipStream_t stream) {
    const float* hidden = (const float*)d_in[0];
    const float* enc    = (const float*)d_in[1];
    const float* W      = (const float*)d_in[2];
    const float* bias   = (const float*)d_in[3];

    float* ctx  = (float*)d_out;
    float* wbuf = (float*)d_out + (B_ * L_ * H_);

    char* ws = (char*)d_ws;
    const size_t NEED_FAST = 209784832;

    if (ws_size >= NEED_FAST) {
        _Float16* encB  = (_Float16*)ws;                     // 134217728 B  (fragment-tiled)
        float*    Upart = (float*)(ws + 134217728);          //  16777216 B  (4 ks x 8 b x 64 x 2048 f32)
        _Float16* w16h  = (_Float16*)(ws + 150994944);       //   4194304 B
        _Float16* w16l  = (_Float16*)(ws + 155189248);       //   4194304 B
        _Float16* vh    = (_Float16*)(ws + 159383552);       //   2097152 B
        _Float16* vl    = (_Float16*)(ws + 161480704);       //   2097152 B
        _Float16* watile = vh;   // 4 MB alias over vh+vl (dead after kcs; written by k3c)
        float* partM = (float*)(ws + 163577856);
        float* partD = partM + 8 * 16 * 64;
        float* fm    = partD + 8 * 16 * 64;
        float* fdinv = fm + 512;

        hipMemsetAsync(ctx, 0, (size_t)B_ * L_ * H_ * sizeof(float), stream);
        kv2_kernel<<<dim3(8, 32), 256, 0, stream>>>(hidden, W, vh, vl);
        kcast_kernel<<<dim3(64, 4), 256, 0, stream>>>(W, w16h, w16l);
        kcs_kernel<<<2048, 256, 0, stream>>>(enc, encB, vh, vl, wbuf);
        k3a_kernel<<<dim3(8, 16), 256, 0, stream>>>(wbuf, partM, partD);
        k3b_kernel<<<1, 512, 0, stream>>>(partM, partD, fm, fdinv);
        k3c_kernel<<<1024, 256, 0, stream>>>(wbuf, fm, fdinv, watile);
        kU_kernel<<<dim3(8, 32, 4), 256, 0, stream>>>(watile, encB, Upart);
        kC_kernel<<<dim3(16, 8, 4), 256, 0, stream>>>(Upart, w16h, w16l, bias, ctx);
    } else {
        _Float16* reduced = (_Float16*)ws;                       // 67108864 B
        float* V     = (float*)(ws + 67108864);                  //  4194304 B
        float* partM = (float*)(ws + 71303168);
        float* partD = partM + 8 * 16 * 64;
        float* fm    = partD + 8 * 16 * 64;
        float* fdinv = fm + 512;
        float* sb    = fdinv + 512;

        hipMemsetAsync(ctx, 0, (size_t)B_ * L_ * H_ * sizeof(float), stream);
        ksb_kernel<<<8, 256, 0, stream>>>(hidden, bias, sb);
        kv_kernel<<<dim3(8, 32), 256, 0, stream>>>(hidden, W, V);
        k1_kernel<<<dim3(8, 256), 256, 0, stream>>>(enc, W, bias, reduced);
        ks_kernel<<<dim3(64, 8), 256, 0, stream>>>(enc, V, sb, wbuf);
        k3a_kernel<<<dim3(8, 16), 256, 0, stream>>>(wbuf, partM, partD);
        k3b_kernel<<<1, 512, 0, stream>>>(partM, partD, fm, fdinv);
        k3c_kernel<<<1024, 256, 0, stream>>>(wbuf, fm, fdinv, (_Float16*)nullptr);
        k4_kernel<<<dim3(8, 4, 16), 256, 0, stream>>>(wbuf, reduced, ctx);
    }
}

// Round 12
// 598.623 us; speedup vs baseline: 1.2729x; 1.0674x over previous
//
#include <hip/hip_runtime.h>

// DotProductAttention: H=1024, B=8, S=4096, L=64
// inputs: d_in[0]=hidden f32 [L,B,H], d_in[1]=enc f32 [B,S,2H], d_in[2]=W f32 [H,2H], d_in[3]=bias f32 [H]
// out: context f32 [B,L,H] (524288) then weights f32 [B,S,L] (2097152)
//
// FAST path (ws_size >= 209784832):
//   ctx = (softmax(scores))^T @ (enc@W^T + b)  ==  U@W^T + b  with U = w^T@enc
//   kv2p+kvc (r11): V=W^T.hidden split over 8 h-quarters (2048 blocks, 8 iters each;
//        was 256 blocks x 64 serial iters = 1 block/CU latency-bound) -> f32 partials
//        -> reduce + fp16 hi/lo fragment cast. Numerically identical sum.
//   kcs (r10): enc fp32 -> f16 hi/lo LDS planes; fused score MFMA; encB fragment emit.
//   softmax k3a/b (exact fp32); k3c: contiguous f16x8 watile store.
//   kU (r8): LDS-free, barrier-free fragment GEMM.
//   kC (r8): K-split x4, atomicAdd epilogue (bias from kq==0), ctx memset.
// FALLBACK path: round-2 kernels verbatim (known-pass, 986 us).

#define H_ 1024
#define B_ 8
#define S_ 4096
#define L_ 64
#define K2H 2048

typedef _Float16 f16x8 __attribute__((ext_vector_type(8)));
typedef _Float16 f16x4 __attribute__((ext_vector_type(4)));
typedef float f32x4 __attribute__((ext_vector_type(4)));

// Fragment layout (A/B operand of mfma 16x16x32 f16), rows=m-or-n, k:
//   tile = (row/16, k/32); lane = ((k%32)/8)*16 + row%16, elem = k%8
//   linear = (tile_row*NTK + tile_k)*512 + lane*8 + elem
// encB layout: [b][ct=chan/16 (128)][st=(s%4096)/32 (128)][512] with (row=chan, k=s).

// ---------------- kcast: fp32 [rows][2048] -> fragment-tiled fp16 hi (+ optional lo) ----------------
__global__ __launch_bounds__(256) void kcast_kernel(const float* __restrict__ src,
                                                    _Float16* __restrict__ hi,
                                                    _Float16* __restrict__ lo) {
    __shared__ float T[16][516];
    const int t = threadIdx.x;
    const int slab = blockIdx.x, ksec = blockIdx.y;
    const float* sp = src + (size_t)slab * 16 * K2H + ksec * 512;
#pragma unroll
    for (int r = 0; r < 8; r++) {
        int lin = r * 1024 + t * 4;
        int row = lin >> 9, col = lin & 511;
        float4 v = *(const float4*)(sp + (size_t)row * K2H + col);
        T[row][col] = v.x; T[row][col + 1] = v.y; T[row][col + 2] = v.z; T[row][col + 3] = v.w;
    }
    __syncthreads();
    const size_t obase = ((size_t)slab * 64 + ksec * 16) * 512;
#pragma unroll
    for (int r = 0; r < 4; r++) {
        int c = r * 256 + t;
        int kt = c >> 6, lam = c & 63;
        int m = lam & 15, kb = kt * 32 + (lam >> 4) * 8;
        f16x8 h, l;
#pragma unroll
        for (int e = 0; e < 8; e++) {
            float x = T[m][kb + e];
            _Float16 hh = (_Float16)x;
            h[e] = hh;
            l[e] = (_Float16)(x - (float)hh);
        }
        *(f16x8*)(hi + obase + (size_t)c * 8) = h;
        if (lo) *(f16x8*)(lo + obase + (size_t)c * 8) = l;
    }
}

// ---------------- kcs: enc cast + fused score GEMM + encB fragment emit ----------------
// grid 2048 (slab = 16 enc rows); block 256 = 4 waves, 33.3KB LDS -> 4 blocks/CU.
__global__ __launch_bounds__(256, 4) void kcs_kernel(const float* __restrict__ enc,
                                                     _Float16* __restrict__ encB,
                                                     const _Float16* __restrict__ vh,
                                                     const _Float16* __restrict__ vl,
                                                     float* __restrict__ scores) {
    __shared__ _Float16 TT[2][16][520];   // hi/lo planes; stride 520 f16 = 16B-aligned rows
    const int t = threadIdx.x;
    const int slab = blockIdx.x;
    const int b = slab >> 8;
    const int w = t >> 6, lane = t & 63;
    const int ml = lane & 15, q = lane >> 4;
    f32x4 acc[4] = {};

    const float* sp0 = enc + (size_t)slab * (16 * K2H);
    float4 rbuf[8];
#pragma unroll
    for (int r = 0; r < 8; r++) {
        int lin = r * 1024 + t * 4;
        rbuf[r] = *(const float4*)(sp0 + (size_t)(lin >> 9) * K2H + (lin & 511));
    }
    const int qb = (slab & 1) * 2;          // s%32 upper-half flag for this slab
    const int st = (slab & 255) >> 1;       // s-tile WITHIN batch b (r10 fix)

    for (int ksec = 0; ksec < 4; ksec++) {
        // write phase: cast regs -> hi/lo LDS planes
#pragma unroll
        for (int r = 0; r < 8; r++) {
            int lin = r * 1024 + t * 4;
            int row = lin >> 9, col = lin & 511;
            float4 v = rbuf[r];
            f16x4 h4, l4;
            h4[0] = (_Float16)v.x; h4[1] = (_Float16)v.y;
            h4[2] = (_Float16)v.z; h4[3] = (_Float16)v.w;
            l4[0] = (_Float16)(v.x - (float)h4[0]);
            l4[1] = (_Float16)(v.y - (float)h4[1]);
            l4[2] = (_Float16)(v.z - (float)h4[2]);
            l4[3] = (_Float16)(v.w - (float)h4[3]);
            *(f16x4*)&TT[0][row][col] = h4;
            *(f16x4*)&TT[1][row][col] = l4;
        }
        __syncthreads();
        // issue next ksec's global loads now; they fly under the compute phase
        if (ksec < 3) {
            const float* sp = sp0 + (ksec + 1) * 512;
#pragma unroll
            for (int r = 0; r < 8; r++) {
                int lin = r * 1024 + t * 4;
                rbuf[r] = *(const float4*)(sp + (size_t)(lin >> 9) * K2H + (lin & 511));
            }
        }
        // encB fragment store (reads stable TT[0]; contiguous half-tile global bursts)
#pragma unroll
        for (int p = 0; p < 4; p++) {
            const int pid = p * 256 + t;
            const int ctl = pid >> 5;              // local chan-tile 0..31
            const int w5 = pid & 31;
            const int oct = w5 >> 4, c = w5 & 15;  // s-octet in slab, chan%16
            f16x8 v;
#pragma unroll
            for (int e = 0; e < 8; e++) v[e] = TT[0][oct * 8 + e][ctl * 16 + c];
            const int ctg = ksec * 32 + ctl;
            const size_t off = (((size_t)(b * 128 + ctg)) * 128 + st) * 512
                             + (size_t)((qb + oct) * 16 + c) * 8;
            *(f16x8*)(encB + off) = v;
        }
        // compute phase
#pragma unroll
        for (int r = 0; r < 4; r++) {
            const int ktl = r * 4 + w;
            const int kb = ktl * 32 + q * 8;
            f16x8 h = *(const f16x8*)&TT[0][ml][kb];
            f16x8 l = *(const f16x8*)&TT[1][ml][kb];
            const int ktg = ksec * 16 + ktl;
            const size_t vbase = (((size_t)(b * 4) * 64) + ktg) * 512 + (size_t)lane * 8;
#pragma unroll
            for (int lt = 0; lt < 4; lt++) {
                f16x8 bH = *(const f16x8*)(vh + vbase + (size_t)lt * 32768);
                f16x8 bL = *(const f16x8*)(vl + vbase + (size_t)lt * 32768);
                acc[lt] = __builtin_amdgcn_mfma_f32_16x16x32_f16(h, bH, acc[lt], 0, 0, 0);
                acc[lt] = __builtin_amdgcn_mfma_f32_16x16x32_f16(l, bH, acc[lt], 0, 0, 0);
                acc[lt] = __builtin_amdgcn_mfma_f32_16x16x32_f16(h, bL, acc[lt], 0, 0, 0);
            }
        }
        __syncthreads();   // TT consumed before next ksec overwrite
    }
    // cross-wave reduce: partials -> scores (P aliases TT storage; TT is dead)
    float (*P)[16][66] = reinterpret_cast<float (*)[16][66]>(&TT[0][0][0]);
#pragma unroll
    for (int lt = 0; lt < 4; lt++)
#pragma unroll
        for (int r = 0; r < 4; r++)
            P[w][q * 4 + r][lt * 16 + ml] = acc[lt][r];
    __syncthreads();
    const int s0 = (slab & 255) * 16;
#pragma unroll
    for (int u = 0; u < 4; u++) {
        const int idx = u * 256 + t;
        const int srow = idx >> 6, l = idx & 63;
        float v = P[0][srow][l] + P[1][srow][l] + P[2][srow][l] + P[3][srow][l];
        scores[(size_t)b * (S_ * L_) + (size_t)(s0 + srow) * L_ + l] = v;
    }
}

// ---------------- kv2p: Vpart[hq][b][l][k] = sum_{h in hq-slice} W[h][k]*hidden[l][b][h] ----------------
// grid (8 b, 32 kc, 8 hq), block 256. 2048 blocks (8/CU), 8 h-iterations each (was 64).
__global__ __launch_bounds__(256) void kv2p_kernel(const float* __restrict__ hidden,
                                                   const float* __restrict__ W,
                                                   float* __restrict__ Vpart) {
    __shared__ float Ah[64][17];
    __shared__ float Wt[16][64];
    const int b = blockIdx.x;
    const int k0 = blockIdx.y * 64;
    const int hq = blockIdx.z;
    const int t = threadIdx.x;
    const int lt = t & 15, kt = t >> 4;
    float acc[4][4];
#pragma unroll
    for (int i = 0; i < 4; i++)
#pragma unroll
        for (int j = 0; j < 4; j++) acc[i][j] = 0.f;

    const int ar = t >> 2, ac4 = (t & 3) * 4;
    const int wrow = t >> 4, wc4 = (t & 15) * 4;

    for (int h0 = hq * 128; h0 < hq * 128 + 128; h0 += 16) {
        float4 av = *(const float4*)(hidden + (size_t)ar * (B_ * H_) + b * H_ + h0 + ac4);
        Ah[ar][ac4 + 0] = av.x; Ah[ar][ac4 + 1] = av.y; Ah[ar][ac4 + 2] = av.z; Ah[ar][ac4 + 3] = av.w;
        *(float4*)&Wt[wrow][wc4] = *(const float4*)(W + (size_t)(h0 + wrow) * K2H + k0 + wc4);
        __syncthreads();
#pragma unroll
        for (int hh = 0; hh < 16; hh++) {
            float a0 = Ah[lt * 4 + 0][hh], a1 = Ah[lt * 4 + 1][hh];
            float a2 = Ah[lt * 4 + 2][hh], a3 = Ah[lt * 4 + 3][hh];
            float4 wv = *(const float4*)&Wt[hh][kt * 4];
            acc[0][0] += a0 * wv.x; acc[0][1] += a0 * wv.y; acc[0][2] += a0 * wv.z; acc[0][3] += a0 * wv.w;
            acc[1][0] += a1 * wv.x; acc[1][1] += a1 * wv.y; acc[1][2] += a1 * wv.z; acc[1][3] += a1 * wv.w;
            acc[2][0] += a2 * wv.x; acc[2][1] += a2 * wv.y; acc[2][2] += a2 * wv.z; acc[2][3] += a2 * wv.w;
            acc[3][0] += a3 * wv.x; acc[3][1] += a3 * wv.y; acc[3][2] += a3 * wv.z; acc[3][3] += a3 * wv.w;
        }
        __syncthreads();
    }
#pragma unroll
    for (int i = 0; i < 4; i++) {
        float4 o; o.x = acc[i][0]; o.y = acc[i][1]; o.z = acc[i][2]; o.w = acc[i][3];
        *(float4*)(Vpart + (((size_t)(hq * 8 + b)) * 64 + lt * 4 + i) * K2H + k0 + kt * 4) = o;
    }
}

// ---------------- kvc: V = sum_hq Vpart -> fp16 hi/lo fragment planes ----------------
// grid (8 b, 32 kc), block 256. Coalesced 256B partial reads; old-kv2 epilogue mapping.
__global__ __launch_bounds__(256) void kvc_kernel(const float* __restrict__ Vpart,
                                                  _Float16* __restrict__ vh,
                                                  _Float16* __restrict__ vl) {
    const int b = blockIdx.x;
    const int k0 = blockIdx.y * 64;
    const int t = threadIdx.x;
#pragma unroll
    for (int u = 0; u < 4; u++) {
        const int uid = u * 256 + t;
        const int l = uid >> 4;
        const int k4 = (uid & 15) * 4;
        float4 s = {0.f, 0.f, 0.f, 0.f};
#pragma unroll
        for (int hq = 0; hq < 8; hq++) {
            float4 v = *(const float4*)(Vpart + (((size_t)(hq * 8 + b)) * 64 + l) * K2H + k0 + k4);
            s.x += v.x; s.y += v.y; s.z += v.z; s.w += v.w;
        }
        const float sv[4] = {s.x, s.y, s.z, s.w};
        const int ltile = l >> 4, lam = l & 15;
#pragma unroll
        for (int j = 0; j < 4; j++) {
            const int k = k0 + k4 + j;
            const size_t idx = (((size_t)(b * 4 + ltile) * 64) + (k >> 5)) * 512
                             + (size_t)((((k >> 3) & 3) * 16 + lam) * 8 + (k & 7));
            float v = sv[j];
            _Float16 hh = (_Float16)v;
            vh[idx] = hh;
            vl[idx] = (_Float16)(v - (float)hh);
        }
    }
}

// ---------------- kU: U[ks][b][l][chan] = sum_{s} watile[l][s] * encB[chan][s] ----------------
// grid (8 b, 32 nc, 4 ks), block 256 = 4 waves (2m x 2n). LDS-free, barrier-free:
// A and B fragments are direct coalesced global f16x8 loads (1KB/instr/wave).
__global__ __launch_bounds__(256) void kU_kernel(const _Float16* __restrict__ wa,
                                                 const _Float16* __restrict__ encB,
                                                 float* __restrict__ Upart) {
    const int t = threadIdx.x;
    const int b = blockIdx.x, nc = blockIdx.y, ks = blockIdx.z;
    const int w = t >> 6, lane = t & 63;
    const int ml = lane & 15, q = lane >> 4;
    const int wm = w >> 1, wn = w & 1;
    f32x4 acc[2][2] = {};

    for (int it = 0; it < 32; ++it) {
        const int stile = ks * 32 + it;
        f16x8 bf[2];
#pragma unroll
        for (int j = 0; j < 2; j++) {
            const int ct = nc * 4 + wn * 2 + j;
            bf[j] = *(const f16x8*)(encB + (((size_t)(b * 128 + ct)) * 128 + stile) * 512
                                     + (size_t)lane * 8);
        }
#pragma unroll
        for (int i = 0; i < 2; i++) {
            f16x8 a = *(const f16x8*)(wa + (((size_t)(b * 4 + wm * 2 + i)) * 128 + stile) * 512
                                       + (size_t)lane * 8);
#pragma unroll
            for (int j = 0; j < 2; j++)
                acc[i][j] = __builtin_amdgcn_mfma_f32_16x16x32_f16(a, bf[j], acc[i][j], 0, 0, 0);
        }
    }
#pragma unroll
    for (int i = 0; i < 2; i++)
#pragma unroll
        for (int j = 0; j < 2; j++)
#pragma unroll
            for (int r = 0; r < 4; r++) {
                const int l = wm * 32 + i * 16 + q * 4 + r;
                const int ch = nc * 64 + (wn * 2 + j) * 16 + ml;
                Upart[(((size_t)(ks * 8 + b)) * 64 + l) * K2H + ch] = acc[i][j][r];
            }
}

// ---------------- kC: ctx[b][l][h] += sum_{k in kq-quarter} Usum[b][l][k]*W[h][k] (+bias once) ----------------
// grid (16 hc, 8 b, 4 kq), block 256 = 4 waves. 512 blocks; atomic f32 accumulation.
__global__ __launch_bounds__(256) void kC_kernel(const float* __restrict__ Upart,
                                                 const _Float16* __restrict__ w16h,
                                                 const _Float16* __restrict__ w16l,
                                                 const float* __restrict__ bias,
                                                 float* __restrict__ ctx) {
    __shared__ _Float16 AsH[64][40], AsL[64][40];
    const int t = threadIdx.x;
    const int hc = blockIdx.x, b = blockIdx.y, kq = blockIdx.z;
    const int w = t >> 6, lane = t & 63;
    const int ml = lane & 15, q = lane >> 4;
    const int wm = w >> 1, wn = w & 1;
    f32x4 acc[2][2] = {};
    const int r0 = t >> 2, c8 = (t & 3) * 8;

    for (int k0 = kq * 512; k0 < kq * 512 + 512; k0 += 32) {
        float xv[8];
#pragma unroll
        for (int e = 0; e < 8; e++) xv[e] = 0.f;
        const size_t ub = ((size_t)b * 64 + r0) * K2H + k0 + c8;
#pragma unroll
        for (int p = 0; p < 4; p++) {
            const float* up = Upart + (size_t)p * (8 * 64 * K2H) + ub;
            float4 u0 = *(const float4*)up, u1 = *(const float4*)(up + 4);
            xv[0] += u0.x; xv[1] += u0.y; xv[2] += u0.z; xv[3] += u0.w;
            xv[4] += u1.x; xv[5] += u1.y; xv[6] += u1.z; xv[7] += u1.w;
        }
        f16x8 hh, ll;
#pragma unroll
        for (int e = 0; e < 8; e++) {
            _Float16 hv = (_Float16)xv[e];
            hh[e] = hv;
            ll[e] = (_Float16)(xv[e] - (float)hv);
        }
        *(f16x8*)&AsH[r0][c8] = hh;
        *(f16x8*)&AsL[r0][c8] = ll;
        __syncthreads();
        const int kt = k0 >> 5;
        f16x8 bH[2], bL[2];
#pragma unroll
        for (int j = 0; j < 2; j++) {
            const size_t wb = (((size_t)(hc * 4 + wn * 2 + j)) * 64 + kt) * 512 + (size_t)lane * 8;
            bH[j] = *(const f16x8*)(w16h + wb);
            bL[j] = *(const f16x8*)(w16l + wb);
        }
#pragma unroll
        for (int i = 0; i < 2; i++) {
            f16x8 aH = *(const f16x8*)&AsH[wm * 32 + i * 16 + ml][q * 8];
            f16x8 aL = *(const f16x8*)&AsL[wm * 32 + i * 16 + ml][q * 8];
#pragma unroll
            for (int j = 0; j < 2; j++) {
                acc[i][j] = __builtin_amdgcn_mfma_f32_16x16x32_f16(aH, bH[j], acc[i][j], 0, 0, 0);
                acc[i][j] = __builtin_amdgcn_mfma_f32_16x16x32_f16(aL, bH[j], acc[i][j], 0, 0, 0);
                acc[i][j] = __builtin_amdgcn_mfma_f32_16x16x32_f16(aH, bL[j], acc[i][j], 0, 0, 0);
            }
        }
        __syncthreads();
    }
#pragma unroll
    for (int i = 0; i < 2; i++)
#pragma unroll
        for (int j = 0; j < 2; j++) {
            const int h = hc * 64 + wn * 32 + j * 16 + ml;
            const float bv = (kq == 0) ? bias[h] : 0.f;
#pragma unroll
            for (int r = 0; r < 4; r++) {
                const int l = wm * 32 + i * 16 + q * 4 + r;
                atomicAdd(ctx + (((size_t)(b * 64 + l)) << 10) + h, acc[i][j][r] + bv);
            }
        }
}

// ================= fallback (round-2) kernels =================

__global__ __launch_bounds__(256) void ksb_kernel(const float* __restrict__ hidden,
                                                  const float* __restrict__ bias,
                                                  float* __restrict__ sb) {
    const int b = blockIdx.x, t = threadIdx.x;
    const int l = t & 63, j = t >> 6;
    const float* hp = hidden + (size_t)l * (B_ * H_) + b * H_ + j * 256;
    const float* bp = bias + j * 256;
    float s = 0.f;
    for (int i = 0; i < 64; i++) {
        float4 h4 = *(const float4*)(hp + i * 4);
        float4 b4 = *(const float4*)(bp + i * 4);
        s += h4.x * b4.x + h4.y * b4.y + h4.z * b4.z + h4.w * b4.w;
    }
    __shared__ float red[256];
    red[t] = s; __syncthreads();
    if (t < 128) red[t] += red[t + 128];
    __syncthreads();
    if (t < 64) sb[b * 64 + t] = red[t] + red[t + 64];
}

__global__ __launch_bounds__(256) void kv_kernel(const float* __restrict__ hidden,
                                                 const float* __restrict__ W,
                                                 float* __restrict__ V) {
    __shared__ float Ah[64][17];
    __shared__ float Wt[16][64];
    const int b = blockIdx.x;
    const int k0 = blockIdx.y * 64;
    const int t = threadIdx.x;
    const int lt = t & 15, kt = t >> 4;
    float acc[4][4];
#pragma unroll
    for (int i = 0; i < 4; i++)
#pragma unroll
        for (int j = 0; j < 4; j++) acc[i][j] = 0.f;

    const int ar = t >> 2, ac4 = (t & 3) * 4;
    const int wrow = t >> 4, wc4 = (t & 15) * 4;

    for (int h0 = 0; h0 < H_; h0 += 16) {
        float4 av = *(const float4*)(hidden + (size_t)ar * (B_ * H_) + b * H_ + h0 + ac4);
        Ah[ar][ac4 + 0] = av.x; Ah[ar][ac4 + 1] = av.y; Ah[ar][ac4 + 2] = av.z; Ah[ar][ac4 + 3] = av.w;
        *(float4*)&Wt[wrow][wc4] = *(const float4*)(W + (size_t)(h0 + wrow) * K2H + k0 + wc4);
        __syncthreads();
#pragma unroll
        for (int hh = 0; hh < 16; hh++) {
            float a0 = Ah[lt * 4 + 0][hh], a1 = Ah[lt * 4 + 1][hh];
            float a2 = Ah[lt * 4 + 2][hh], a3 = Ah[lt * 4 + 3][hh];
            float4 wv = *(const float4*)&Wt[hh][kt * 4];
            acc[0][0] += a0 * wv.x; acc[0][1] += a0 * wv.y; acc[0][2] += a0 * wv.z; acc[0][3] += a0 * wv.w;
            acc[1][0] += a1 * wv.x; acc[1][1] += a1 * wv.y; acc[1][2] += a1 * wv.z; acc[1][3] += a1 * wv.w;
            acc[2][0] += a2 * wv.x; acc[2][1] += a2 * wv.y; acc[2][2] += a2 * wv.z; acc[2][3] += a2 * wv.w;
            acc[3][0] += a3 * wv.x; acc[3][1] += a3 * wv.y; acc[3][2] += a3 * wv.z; acc[3][3] += a3 * wv.w;
        }
        __syncthreads();
    }
#pragma unroll
    for (int i = 0; i < 4; i++) {
        float4 o; o.x = acc[i][0]; o.y = acc[i][1]; o.z = acc[i][2]; o.w = acc[i][3];
        *(float4*)(V + (size_t)b * (L_ * K2H) + (lt * 4 + i) * K2H + k0 + kt * 4) = o;
    }
}

__global__ __launch_bounds__(256) void k1_kernel(const float* __restrict__ enc,
                                                 const float* __restrict__ W,
                                                 const float* __restrict__ bias,
                                                 _Float16* __restrict__ reduced) {
    __shared__ _Float16 As[128][40];
    __shared__ _Float16 Bs[128][40];
    const int t = threadIdx.x;
    const int n0 = blockIdx.x * 128;
    const int m0 = blockIdx.y * 128;
    const int w = t >> 6, lane = t & 63;
    const int wr = w >> 1, wc = w & 1;
    const int ml = lane & 15, q = lane >> 4;

    f32x4 acc[4][4];
#pragma unroll
    for (int i = 0; i < 4; i++)
#pragma unroll
        for (int j = 0; j < 4; j++) acc[i][j] = (f32x4){0.f, 0.f, 0.f, 0.f};

    const int r0 = t >> 2;
    const int c8 = (t & 3) * 8;

    for (int k0 = 0; k0 < K2H; k0 += 32) {
#pragma unroll
        for (int j = 0; j < 2; ++j) {
            const int row = r0 + 64 * j;
            const float* pa = enc + (size_t)(m0 + row) * K2H + k0 + c8;
            float4 a0 = *(const float4*)pa, a1 = *(const float4*)(pa + 4);
            f16x8 ha;
            ha[0] = (_Float16)a0.x; ha[1] = (_Float16)a0.y; ha[2] = (_Float16)a0.z; ha[3] = (_Float16)a0.w;
            ha[4] = (_Float16)a1.x; ha[5] = (_Float16)a1.y; ha[6] = (_Float16)a1.z; ha[7] = (_Float16)a1.w;
            *(f16x8*)&As[row][c8] = ha;
            const float* pb = W + (size_t)(n0 + row) * K2H + k0 + c8;
            float4 b0 = *(const float4*)pb, b1 = *(const float4*)(pb + 4);
            f16x8 hb;
            hb[0] = (_Float16)b0.x; hb[1] = (_Float16)b0.y; hb[2] = (_Float16)b0.z; hb[3] = (_Float16)b0.w;
            hb[4] = (_Float16)b1.x; hb[5] = (_Float16)b1.y; hb[6] = (_Float16)b1.z; hb[7] = (_Float16)b1.w;
            *(f16x8*)&Bs[row][c8] = hb;
        }
        __syncthreads();
        f16x8 af[4], bf[4];
#pragma unroll
        for (int i = 0; i < 4; i++) af[i] = *(const f16x8*)&As[wr * 64 + i * 16 + ml][q * 8];
#pragma unroll
        for (int j = 0; j < 4; j++) bf[j] = *(const f16x8*)&Bs[wc * 64 + j * 16 + ml][q * 8];
#pragma unroll
        for (int i = 0; i < 4; i++)
#pragma unroll
            for (int j = 0; j < 4; j++)
                acc[i][j] = __builtin_amdgcn_mfma_f32_16x16x32_f16(af[i], bf[j], acc[i][j], 0, 0, 0);
        __syncthreads();
    }
#pragma unroll
    for (int j = 0; j < 4; j++) {
        const int h = n0 + wc * 64 + j * 16 + ml;
        const float bv = bias[h];
#pragma unroll
        for (int i = 0; i < 4; i++) {
            const int srow = m0 + wr * 64 + i * 16 + q * 4;
#pragma unroll
            for (int r = 0; r < 4; r++)
                reduced[(size_t)(srow + r) * H_ + h] = (_Float16)(acc[i][j][r] + bv);
        }
    }
}

__global__ __launch_bounds__(256) void ks_kernel(const float* __restrict__ enc,
                                                 const float* __restrict__ V,
                                                 const float* __restrict__ sb,
                                                 float* __restrict__ scores) {
    __shared__ _Float16 AsH[64][40], AsL[64][40];
    __shared__ _Float16 BsH[64][40], BsL[64][40];
    const int t = threadIdx.x;
    const int s0 = blockIdx.x * 64;
    const int b = blockIdx.y;
    const int w = t >> 6, lane = t & 63;
    const int ml = lane & 15, q = lane >> 4;

    f32x4 acc[4];
#pragma unroll
    for (int j = 0; j < 4; j++) acc[j] = (f32x4){0.f, 0.f, 0.f, 0.f};

    const int r0 = t >> 2, c8 = (t & 3) * 8;

    for (int k0 = 0; k0 < K2H; k0 += 32) {
        {
            const float* pa = enc + (size_t)(b * S_ + s0 + r0) * K2H + k0 + c8;
            float4 a0 = *(const float4*)pa, a1 = *(const float4*)(pa + 4);
            float xv[8] = {a0.x, a0.y, a0.z, a0.w, a1.x, a1.y, a1.z, a1.w};
            f16x8 hh, ll;
#pragma unroll
            for (int e = 0; e < 8; e++) {
                _Float16 hi = (_Float16)xv[e];
                hh[e] = hi;
                ll[e] = (_Float16)(xv[e] - (float)hi);
            }
            *(f16x8*)&AsH[r0][c8] = hh;
            *(f16x8*)&AsL[r0][c8] = ll;
        }
        {
            const float* pb = V + (size_t)b * (L_ * K2H) + (size_t)r0 * K2H + k0 + c8;
            float4 b0 = *(const float4*)pb, b1 = *(const float4*)(pb + 4);
            float xv[8] = {b0.x, b0.y, b0.z, b0.w, b1.x, b1.y, b1.z, b1.w};
            f16x8 hh, ll;
#pragma unroll
            for (int e = 0; e < 8; e++) {
                _Float16 hi = (_Float16)xv[e];
                hh[e] = hi;
                ll[e] = (_Float16)(xv[e] - (float)hi);
            }
            *(f16x8*)&BsH[r0][c8] = hh;
            *(f16x8*)&BsL[r0][c8] = ll;
        }
        __syncthreads();
        f16x8 aH = *(const f16x8*)&AsH[w * 16 + ml][q * 8];
        f16x8 aL = *(const f16x8*)&AsL[w * 16 + ml][q * 8];
#pragma unroll
        for (int j = 0; j < 4; j++) {
            f16x8 bH = *(const f16x8*)&BsH[j * 16 + ml][q * 8];
            f16x8 bL = *(const f16x8*)&BsL[j * 16 + ml][q * 8];
            acc[j] = __builtin_amdgcn_mfma_f32_16x16x32_f16(aH, bH, acc[j], 0, 0, 0);
            acc[j] = __builtin_amdgcn_mfma_f32_16x16x32_f16(aL, bH, acc[j], 0, 0, 0);
            acc[j] = __builtin_amdgcn_mfma_f32_16x16x32_f16(aH, bL, acc[j], 0, 0, 0);
        }
        __syncthreads();
    }
#pragma unroll
    for (int j = 0; j < 4; j++) {
        const int l = j * 16 + ml;
        const float sbv = sb[b * 64 + l];
        const int srow = s0 + w * 16 + q * 4;
#pragma unroll
        for (int r = 0; r < 4; r++)
            scores[(size_t)b * (S_ * L_) + (size_t)(srow + r) * L_ + l] = acc[j][r] + sbv;
    }
}

__global__ __launch_bounds__(256) void k4_kernel(const float* __restrict__ wbuf,
                                                 const _Float16* __restrict__ reduced,
                                                 float* __restrict__ ctx) {
    __shared__ float Ws[64][64];
    __shared__ _Float16 Rs[64][256];
    const int t = threadIdx.x;
    const int b = blockIdx.x, ht = blockIdx.y, sc = blockIdx.z;
    const int h = ht * 256 + t;
    float acc[64];
#pragma unroll
    for (int l = 0; l < 64; l++) acc[l] = 0.f;

    for (int cc = 0; cc < 4; ++cc) {
        const int sbase = sc * 256 + cc * 64;
#pragma unroll
        for (int j = 0; j < 4; j++) {
            int c = t + 256 * j;
            int row = c >> 4, c4 = (c & 15) * 4;
            *(float4*)&Ws[row][c4] =
                *(const float4*)(wbuf + (size_t)b * (S_ * L_) + (size_t)(sbase + row) * L_ + c4);
        }
#pragma unroll
        for (int j = 0; j < 8; j++) {
            int c = t + 256 * j;
            int row = c >> 5, ch = (c & 31) * 8;
            *(uint4*)&Rs[row][ch] =
                *(const uint4*)(reduced + (size_t)(b * S_ + sbase + row) * H_ + ht * 256 + ch);
        }
        __syncthreads();
        for (int ss = 0; ss < 64; ++ss) {
            float r = (float)Rs[ss][t];
            const float4* wr = (const float4*)&Ws[ss][0];
#pragma unroll
            for (int u = 0; u < 16; u++) {
                float4 wv = wr[u];
                acc[u * 4 + 0] += wv.x * r;
                acc[u * 4 + 1] += wv.y * r;
                acc[u * 4 + 2] += wv.z * r;
                acc[u * 4 + 3] += wv.w * r;
            }
        }
        __syncthreads();
    }
#pragma unroll
    for (int l = 0; l < 64; l++)
        atomicAdd(ctx + (size_t)((b * 64 + l) << 10) + h, acc[l]);
}

// ================= shared (both paths) =================

__global__ __launch_bounds__(256) void k3a_kernel(const float* __restrict__ scores,
                                                  float* __restrict__ partM,
                                                  float* __restrict__ partD) {
    const int b = blockIdx.x, chunk = blockIdx.y;
    const int t = threadIdx.x;
    const int l = t & 63, si = t >> 6;
    const float* p = scores + (size_t)b * (S_ * L_) + (size_t)(chunk * 256 + si * 64) * L_ + l;
    float m = -__builtin_inff(), d = 0.f;
    for (int i = 0; i < 64; i++) {
        float x = p[i * 64];
        if (x > m) { d = d * __expf(m - x) + 1.f; m = x; }
        else d += __expf(x - m);
    }
    __shared__ float sm[256], sd[256];
    sm[t] = m; sd[t] = d; __syncthreads();
    if (t < 128) {
        float m2 = sm[t + 128], d2 = sd[t + 128];
        if (m2 > sm[t]) { sd[t] = sd[t] * __expf(sm[t] - m2) + d2; sm[t] = m2; }
        else sd[t] += d2 * __expf(m2 - sm[t]);
    }
    __syncthreads();
    if (t < 64) {
        float m1 = sm[t], d1 = sd[t], m2 = sm[t + 64], d2 = sd[t + 64];
        if (m2 > m1) { d1 = d1 * __expf(m1 - m2) + d2; m1 = m2; }
        else d1 += d2 * __expf(m2 - m1);
        partM[(b * 16 + chunk) * 64 + t] = m1;
        partD[(b * 16 + chunk) * 64 + t] = d1;
    }
}

__global__ __launch_bounds__(512) void k3b_kernel(const float* __restrict__ partM,
                                                  const float* __restrict__ partD,
                                                  float* __restrict__ fm,
                                                  float* __restrict__ fdinv) {
    const int t = threadIdx.x;
    const int b = t >> 6, l = t & 63;
    float m = -__builtin_inff(), d = 0.f;
    for (int c = 0; c < 16; c++) {
        float pm = partM[(b * 16 + c) * 64 + l];
        float pd = partD[(b * 16 + c) * 64 + l];
        if (pm > m) { d = d * __expf(m - pm) + pd; m = pm; }
        else d += pd * __expf(pm - m);
    }
    fm[t] = m;
    fdinv[t] = 1.0f / d;
}

// k3c: lane owns one l; each thread handles 8 consecutive s.
// wbuf reads/writes stay 256B wave-coalesced; watile store is ONE contiguous f16x8.
__global__ __launch_bounds__(256) void k3c_kernel(float* __restrict__ wbuf,
                                                  const float* __restrict__ fm,
                                                  const float* __restrict__ fdinv,
                                                  _Float16* __restrict__ watile) {
    const int t = threadIdx.x;
    const int l = t & 63;
    const int g = blockIdx.x * 4 + (t >> 6);   // (b, s-octet) id, 0..4095
    const int b = g >> 9;
    const int s0 = (g & 511) * 8;
    const float m = fm[b * 64 + l];
    const float inv = fdinv[b * 64 + l];
    float* wp = wbuf + (size_t)b * (S_ * L_) + (size_t)s0 * L_ + l;
    float y[8];
#pragma unroll
    for (int i = 0; i < 8; i++) y[i] = __expf(wp[i * L_] - m) * inv;
#pragma unroll
    for (int i = 0; i < 8; i++) wp[i * L_] = y[i];
    if (watile) {
        f16x8 o;
#pragma unroll
        for (int i = 0; i < 8; i++) o[i] = (_Float16)y[i];
        const size_t woff = (((size_t)(b * 4 + (l >> 4)) * 128) + (s0 >> 5)) * 512
                          + (size_t)((((s0 >> 3) & 3) * 16 + (l & 15)) * 8);
        *(f16x8*)(watile + woff) = o;
    }
}

extern "C" void kernel_launch(void* const* d_in, const int* in_sizes, int n_in,
                              void* d_out, int out_size, void* d_ws, size_t ws_size,
                              hipStream_t stream) {
    const float* hidden = (const float*)d_in[0];
    const float* enc    = (const float*)d_in[1];
    const float* W      = (const float*)d_in[2];
    const float* bias   = (const float*)d_in[3];

    float* ctx  = (float*)d_out;
    float* wbuf = (float*)d_out + (B_ * L_ * H_);

    char* ws = (char*)d_ws;
    const size_t NEED_FAST = 209784832;

    if (ws_size >= NEED_FAST) {
        _Float16* encB  = (_Float16*)ws;                     // 134217728 B  (fragment-tiled)
        float*    Upart = (float*)(ws + 134217728);          //  16777216 B  (4 ks x 8 b x 64 x 2048 f32)
        _Float16* w16h  = (_Float16*)(ws + 150994944);       //   4194304 B
        _Float16* w16l  = (_Float16*)(ws + 155189248);       //   4194304 B
        _Float16* vh    = (_Float16*)(ws + 159383552);       //   2097152 B
        _Float16* vl    = (_Float16*)(ws + 161480704);       //   2097152 B
        float*    Vpart = (float*)(ws + 163577856);          //  33554432 B  (8 hq x 8 b x 64 x 2048 f32)
        _Float16* watile = vh;   // 4 MB alias over vh+vl (dead after kcs; written by k3c)
        float* partM = (float*)(ws + 197132288);
        float* partD = partM + 8 * 16 * 64;
        float* fm    = partD + 8 * 16 * 64;
        float* fdinv = fm + 512;

        hipMemsetAsync(ctx, 0, (size_t)B_ * L_ * H_ * sizeof(float), stream);
        kv2p_kernel<<<dim3(8, 32, 8), 256, 0, stream>>>(hidden, W, Vpart);
        kvc_kernel<<<dim3(8, 32), 256, 0, stream>>>(Vpart, vh, vl);
        kcast_kernel<<<dim3(64, 4), 256, 0, stream>>>(W, w16h, w16l);
        kcs_kernel<<<2048, 256, 0, stream>>>(enc, encB, vh, vl, wbuf);
        k3a_kernel<<<dim3(8, 16), 256, 0, stream>>>(wbuf, partM, partD);
        k3b_kernel<<<1, 512, 0, stream>>>(partM, partD, fm, fdinv);
        k3c_kernel<<<1024, 256, 0, stream>>>(wbuf, fm, fdinv, watile);
        kU_kernel<<<dim3(8, 32, 4), 256, 0, stream>>>(watile, encB, Upart);
        kC_kernel<<<dim3(16, 8, 4), 256, 0, stream>>>(Upart, w16h, w16l, bias, ctx);
    } else {
        _Float16* reduced = (_Float16*)ws;                       // 67108864 B
        float* V     = (float*)(ws + 67108864);                  //  4194304 B
        float* partM = (float*)(ws + 71303168);
        float* partD = partM + 8 * 16 * 64;
        float* fm    = partD + 8 * 16 * 64;
        float* fdinv = fm + 512;
        float* sb    = fdinv + 512;

        hipMemsetAsync(ctx, 0, (size_t)B_ * L_ * H_ * sizeof(float), stream);
        ksb_kernel<<<8, 256, 0, stream>>>(hidden, bias, sb);
        kv_kernel<<<dim3(8, 32), 256, 0, stream>>>(hidden, W, V);
        k1_kernel<<<dim3(8, 256), 256, 0, stream>>>(enc, W, bias, reduced);
        ks_kernel<<<dim3(64, 8), 256, 0, stream>>>(enc, V, sb, wbuf);
        k3a_kernel<<<dim3(8, 16), 256, 0, stream>>>(wbuf, partM, partD);
        k3b_kernel<<<1, 512, 0, stream>>>(partM, partD, fm, fdinv);
        k3c_kernel<<<1024, 256, 0, stream>>>(wbuf, fm, fdinv, (_Float16*)nullptr);
        k4_kernel<<<dim3(8, 4, 16), 256, 0, stream>>>(wbuf, reduced, ctx);
    }
}